// Round 1
// baseline (218.538 us; speedup 1.0000x reference)
//
#include <hip/hip_runtime.h>
#include <math.h>

// Problem constants
#define B 8192
#define E 1024
#define D 384
#define H 64
#define R 8
#define NCHUNK 16
#define CHUNK_E 64
#define NPOS 17408          // 16384 + 8*128 per-router pad-to-128

// ws byte offsets (total ~10 MB; ws is 256 MiB per harness fill)
#define WS_CNT    0u          // int[8]  counts (atomic)
#define WS_CUR    32u         // int[8]  cursors (atomic)
#define WS_PS     64u         // float[8] prob sums (atomic)
#define WS_OFFS   96u         // int[8]  padded segment bases
#define WS_TOP2   256u        // int2[B]
#define WS_GW     65792u      // float2[B]
#define WS_POSM   131328u     // int2[B]
#define WS_LIST   196864u     // int[NPOS]
#define WS_EVN    266496u     // float[8*64*1024] evnT[r][h][e]
#define WS_XUN    2363648u    // float[NPOS*64]   xunP[pos][h]
#define WS_C      6820096u    // float[NPOS*16]   C[pos][chunk]
#define WS_EVNN   7934208u    // float[8*1024*64] evnN[r][e][h]

// ---------------- gate: lane = (sample, router); LDS-transposed gate_w -----
__global__ __launch_bounds__(256) void k_gate(
    const float* __restrict__ x, const float* __restrict__ gate_w,
    const float* __restrict__ gate_b, int2* __restrict__ top2,
    float2* __restrict__ gwv, int* __restrict__ counts, float* __restrict__ ps)
{
  __shared__ __align__(16) float gwT[R * 388];
  __shared__ float psl[R];
  __shared__ int   cl[R];
  int tid = threadIdx.x;
  for (int idx = tid; idx < D * R; idx += 256) {
    int k = idx >> 3, r = idx & 7;
    gwT[r * 388 + k] = gate_w[idx];
  }
  if (tid < R) { psl[tid] = 0.f; cl[tid] = 0; }
  __syncthreads();

  int l = tid & 63;
  int r = tid & 7;
  int b = blockIdx.x * 32 + (tid >> 3);
  float acc = gate_b[r];
  const float4* x4 = (const float4*)(x + (size_t)b * D);
  const float*  gr = gwT + r * 388;
#pragma unroll 4
  for (int q = 0; q < 96; ++q) {
    float4 xv = x4[q];
    float4 gv = *(const float4*)&gr[q * 4];
    acc = fmaf(xv.x, gv.x, acc);
    acc = fmaf(xv.y, gv.y, acc);
    acc = fmaf(xv.z, gv.z, acc);
    acc = fmaf(xv.w, gv.w, acc);
  }
  float lv[R];
#pragma unroll
  for (int rr = 0; rr < R; ++rr) lv[rr] = __shfl(acc, (l & ~7) + rr);
  int i0 = 0; float v0 = lv[0];
#pragma unroll
  for (int rr = 1; rr < R; ++rr) if (lv[rr] > v0) { v0 = lv[rr]; i0 = rr; }
  int i1 = (i0 == 0) ? 1 : 0; float v1 = lv[i1];
#pragma unroll
  for (int rr = 0; rr < R; ++rr)
    if (rr != i0 && lv[rr] > v1) { v1 = lv[rr]; i1 = rr; }
  float se = 0.f;
#pragma unroll
  for (int rr = 0; rr < R; ++rr) se += expf(lv[rr] - v0);
  float p = expf(acc - v0) / se;
  if (r == 0) {
    float e10 = expf(v1 - v0);
    top2[b] = make_int2(i0, i1);
    gwv[b]  = make_float2(1.f / (1.f + e10), e10 / (1.f + e10));
  }
  float pa = p;
  int   ca = (r == i0 ? 1 : 0) + (r == i1 ? 1 : 0);
#pragma unroll
  for (int m = 8; m < 64; m <<= 1) {
    pa += __shfl_xor(pa, m);
    ca += __shfl_xor(ca, m);
  }
  if (l < 8) { atomicAdd(&psl[r], pa); atomicAdd(&cl[r], ca); }
  __syncthreads();
  if (tid < R) { atomicAdd(&ps[tid], psl[tid]); atomicAdd(&counts[tid], cl[tid]); }
}

// ---------------- scatter: per-router lists (pad-128 bases) + aux + offs ---
__global__ __launch_bounds__(256) void k_scatter(
    const int2* __restrict__ top2, const int* __restrict__ counts,
    const float* __restrict__ ps, int* __restrict__ cursors,
    int* __restrict__ list, int2* __restrict__ posmap,
    int* __restrict__ offs_g, float* __restrict__ out_aux)
{
  __shared__ int lc[R];
  __shared__ int lbase[R];
  __shared__ int offs[R];
  int tid = threadIdx.x;
  if (tid < R) lc[tid] = 0;
  __syncthreads();
  if (tid == 0) {
    int o = 0;
    for (int r2 = 0; r2 < R; ++r2) { offs[r2] = o; o += (min(counts[r2], B) + 127) & ~127; }
  }
  __syncthreads();
  int b = min(blockIdx.x * 256 + tid, B - 1);
  int2 t = top2[b];
  t.x &= 7; t.y &= 7;
  int p0 = atomicAdd(&lc[t.x], 1);
  int p1 = atomicAdd(&lc[t.y], 1);
  __syncthreads();
  if (tid < R) lbase[tid] = atomicAdd(&cursors[tid], lc[tid]);
  __syncthreads();
  int i0 = min(offs[t.x] + lbase[t.x] + p0, NPOS - 1);
  int i1 = min(offs[t.y] + lbase[t.y] + p1, NPOS - 1);
  list[i0] = b * 2 + 0;
  list[i1] = b * 2 + 1;
  posmap[b] = make_int2(i0, i1);
  if (blockIdx.x == 0 && tid == 0) {
    float s = 0.f;
    for (int r2 = 0; r2 < R; ++r2) {
      s += (ps[r2] / (float)B) * ((float)min(counts[r2], B) / (float)B);
      offs_g[r2] = offs[r2];
    }
    out_aux[0] = (float)R * s * 0.05f;
  }
}

// ---------------- projgemm: fused full-K GEMM + bias + l2norm + writeout ---
// 256 threads; tile 64 rows x 64 h (full H); 4x4/thread; 6 k-stages of 64.
// grid 400 = 128 evn tiles + 272 xun tiles (pad-128 segs).
// Epilogue: row L2-norm via 16-lane shfl_xor reduce; writes
//   evn: evnN[r][e][h] (direct f4) + evnT[r][h][e] (LDS stride-66 transpose)
//   xun: xunP[pos][h]  (direct f4)
__global__ __launch_bounds__(256) void k_projgemm(
    const float* __restrict__ re, const float* __restrict__ x,
    const float* __restrict__ Vw, const float* __restrict__ Uw,
    const float* __restrict__ Vb, const float* __restrict__ Ub,
    const int* __restrict__ list, const int* __restrict__ counts,
    const int* __restrict__ offs, float* __restrict__ evnT,
    float* __restrict__ evnN, float* __restrict__ xunP)
{
  __shared__ __align__(16) float lds[8192];
  float* At = lds;            // [k][row] 64x64
  float* Wt = lds + 4096;     // [k][h]   64x64
  int tid = threadIdx.x;
  int tile = blockIdx.x;
  int rowg0 = tile * 64;

  int srow = tid & 63, kq = tid >> 6;           // staging roles
  const float* Wsrc;
  const float* arow;
  int r = 0;
  bool isE = (tile < 128);
  if (isE) {
    r = rowg0 >> 10;
    Wsrc = Vw + (size_t)r * (D * H);
    arow = re + (size_t)((rowg0 & 1023) + srow) * D;
  } else {
    int pos0 = rowg0 - 8192;
    int tot = offs[R - 1] + ((min(counts[R - 1], B) + 127) & ~127);
    if (pos0 >= tot) return;
    for (int rr = 0; rr < R; ++rr) if (pos0 >= offs[rr]) r = rr;
    Wsrc = Uw + (size_t)r * (D * H);
    int gl = list[min(pos0 + srow, NPOS - 1)];
    gl = min(max(gl, 0), 2 * B - 1);
    arow = x + (size_t)(gl >> 1) * D;
  }

  int tr = tid >> 4, tc = tid & 15;             // compute roles: 16 x 16
  float acc[4][4];
#pragma unroll
  for (int i = 0; i < 4; ++i)
#pragma unroll
    for (int j = 0; j < 4; ++j) acc[i][j] = 0.f;

  for (int kt = 0; kt < 6; ++kt) {
    int kb = kt * 64;
    __syncthreads();
#pragma unroll
    for (int q = 0; q < 4; ++q) {               // A: [row][k] -> At[k][row]
      float4 v = *(const float4*)&arow[kb + (kq + 4 * q) * 4];
      int k0 = (kq + 4 * q) * 4;
      At[(k0 + 0) * 64 + srow] = v.x;
      At[(k0 + 1) * 64 + srow] = v.y;
      At[(k0 + 2) * 64 + srow] = v.z;
      At[(k0 + 3) * 64 + srow] = v.w;
    }
#pragma unroll
    for (int q = 0; q < 4; ++q) {               // W: direct [k][h]
      int idx = tid + 256 * q;
      int k = idx >> 4, h4 = idx & 15;
      *(float4*)&Wt[k * 64 + h4 * 4] = *(const float4*)&Wsrc[(size_t)(kb + k) * H + h4 * 4];
    }
    __syncthreads();
#pragma unroll 8
    for (int k = 0; k < 64; ++k) {
      float4 a4 = *(const float4*)&At[k * 64 + tr * 4];
      float4 w4 = *(const float4*)&Wt[k * 64 + tc * 4];
      const float* ap = (const float*)&a4;
      const float* wp = (const float*)&w4;
#pragma unroll
      for (int i = 0; i < 4; ++i)
#pragma unroll
        for (int j = 0; j < 4; ++j) acc[i][j] = fmaf(ap[i], wp[j], acc[i][j]);
    }
  }

  // ---- epilogue: bias + row L2-norm (row = tr*4+i, its 64 h live on 16 tc lanes)
  const float* bsrc = (isE ? Vb : Ub) + r * H + tc * 4;
  float4 bv = *(const float4*)bsrc;
  float vv[4][4];
#pragma unroll
  for (int i = 0; i < 4; ++i) {
    vv[i][0] = acc[i][0] + bv.x;
    vv[i][1] = acc[i][1] + bv.y;
    vv[i][2] = acc[i][2] + bv.z;
    vv[i][3] = acc[i][3] + bv.w;
    float ss = vv[i][0] * vv[i][0] + vv[i][1] * vv[i][1]
             + vv[i][2] * vv[i][2] + vv[i][3] * vv[i][3];
#pragma unroll
    for (int m = 1; m < 16; m <<= 1) ss += __shfl_xor(ss, m);
    float dn = fmaxf(sqrtf(ss), 1e-12f);
    vv[i][0] /= dn; vv[i][1] /= dn; vv[i][2] /= dn; vv[i][3] /= dn;
  }

  if (!isE) {
    int pos0 = rowg0 - 8192;
#pragma unroll
    for (int i = 0; i < 4; ++i) {
      float4 o;
      o.x = vv[i][0]; o.y = vv[i][1]; o.z = vv[i][2]; o.w = vv[i][3];
      *(float4*)&xunP[(size_t)(pos0 + tr * 4 + i) * H + tc * 4] = o;
    }
    return;
  }

  int ebase = rowg0 & 1023;
#pragma unroll
  for (int i = 0; i < 4; ++i) {                 // evnN[r][e][h] direct
    float4 o;
    o.x = vv[i][0]; o.y = vv[i][1]; o.z = vv[i][2]; o.w = vv[i][3];
    *(float4*)&evnN[((size_t)r * 1024 + ebase + tr * 4 + i) * H + tc * 4] = o;
  }
  __syncthreads();                              // all FMA reads of At/Wt done
#pragma unroll
  for (int i = 0; i < 4; ++i)                   // transpose: T[h*66 + row]
#pragma unroll
    for (int j = 0; j < 4; ++j)
      lds[(tc * 4 + j) * 66 + tr * 4 + i] = vv[i][j];
  __syncthreads();
#pragma unroll
  for (int q = 0; q < 4; ++q) {                 // coalesced evnT writes
    int idx = tid + 256 * q;
    int h = idx >> 4, f4 = idx & 15;
    float4 o;
    o.x = lds[h * 66 + f4 * 4 + 0];
    o.y = lds[h * 66 + f4 * 4 + 1];
    o.z = lds[h * 66 + f4 * 4 + 2];
    o.w = lds[h * 66 + f4 * 4 + 3];
    *(float4*)&evnT[(size_t)(r * 64 + h) * 1024 + ebase + f4 * 4] = o;
  }
}

// ---------------- pass1: scores GEMM -> __expf -> chunk sums ---------------
// tile 128 pos x 128 e; 8x8/thread; 32-k double-stage => LDS 32 KB.
__global__ __launch_bounds__(256) void k_pass1(
    const float* __restrict__ evnT, const float* __restrict__ xunP,
    const int* __restrict__ counts, const int* __restrict__ offs,
    float* __restrict__ C)
{
  __shared__ __align__(16) float Xt[32 * 128];
  __shared__ __align__(16) float Et[32 * 128];
  int tid = threadIdx.x;
  int bid = blockIdx.x;
  int et    = bid & 7;
  int stile = (bid >> 3) & 63;
  int r     = bid >> 9;
  int cnt = min(counts[r], B);
  if (cnt <= 0 || stile * 128 >= cnt) return;
  int off = offs[r] + stile * 128;
  int n = min(128, cnt - stile * 128);
  int ebase = et * 128;

  int sg = tid >> 4, egr = tid & 15;
  float acc[8][8];
#pragma unroll
  for (int i = 0; i < 8; ++i)
#pragma unroll
    for (int j = 0; j < 8; ++j) acc[i][j] = 0.f;

  int srow = tid >> 1, shalf = tid & 1;
  int src = min(srow, n - 1);
  const float4* xsrc = (const float4*)(xunP + (size_t)(off + src) * H);

  for (int kst = 0; kst < 2; ++kst) {
    __syncthreads();
    {  // Xt: [pos][h] -> [h-local][s]
#pragma unroll
      for (int q = 0; q < 4; ++q) {
        float4 v = xsrc[kst * 8 + shalf * 4 + q];
        int hb = shalf * 16 + q * 4;
        Xt[(hb + 0) * 128 + srow] = v.x;
        Xt[(hb + 1) * 128 + srow] = v.y;
        Xt[(hb + 2) * 128 + srow] = v.z;
        Xt[(hb + 3) * 128 + srow] = v.w;
      }
    }
    {  // Et: evnT [h][ebase..+128)
#pragma unroll
      for (int q = 0; q < 4; ++q) {
        int idx = tid + 256 * q;
        int h = idx >> 5, e4 = idx & 31;
        *(float4*)&Et[h * 128 + e4 * 4] =
            *(const float4*)(evnT + (size_t)(r * 64 + kst * 32 + h) * 1024 + ebase + e4 * 4);
      }
    }
    __syncthreads();
#pragma unroll 4
    for (int k = 0; k < 32; ++k) {
      float4 xa = *(const float4*)&Xt[k * 128 + sg * 4];
      float4 xb = *(const float4*)&Xt[k * 128 + 64 + sg * 4];
      float4 ea = *(const float4*)&Et[k * 128 + egr * 4];
      float4 eb = *(const float4*)&Et[k * 128 + 64 + egr * 4];
      const float* pa = (const float*)&xa;
      const float* pb = (const float*)&xb;
      const float* qa = (const float*)&ea;
      const float* qb = (const float*)&eb;
#pragma unroll
      for (int i = 0; i < 4; ++i)
#pragma unroll
        for (int j = 0; j < 4; ++j) {
          acc[i][j]         = fmaf(pa[i], qa[j], acc[i][j]);
          acc[i][j + 4]     = fmaf(pa[i], qb[j], acc[i][j + 4]);
          acc[i + 4][j]     = fmaf(pb[i], qa[j], acc[i + 4][j]);
          acc[i + 4][j + 4] = fmaf(pb[i], qb[j], acc[i + 4][j + 4]);
        }
    }
  }

#pragma unroll
  for (int i = 0; i < 8; ++i) {
    float cA = __expf(acc[i][0]) + __expf(acc[i][1]) + __expf(acc[i][2]) + __expf(acc[i][3]);
    float cB = __expf(acc[i][4]) + __expf(acc[i][5]) + __expf(acc[i][6]) + __expf(acc[i][7]);
#pragma unroll
    for (int m = 1; m < 16; m <<= 1) {
      cA += __shfl_xor(cA, m);
      cB += __shfl_xor(cB, m);
    }
    int s = (i < 4) ? (sg * 4 + i) : (64 + sg * 4 + i - 4);
    if (egr == 0 && s < n) {
      C[(size_t)(off + s) * NCHUNK + et * 2]     = cA;
      C[(size_t)(off + s) * NCHUNK + et * 2 + 1] = cB;
    }
  }
}

// ---------------- pass2: chunk-level inverse-CDF, recompute 1 chunk --------
// New: lane = e; evnN row reads (16 f4) + LDS-broadcast xu (16 b128)
// replaces 64 shfl + 64 scalar loads per router.
__global__ __launch_bounds__(256) void k_pass2(
    const float* __restrict__ evnN, const float* __restrict__ xunP,
    const float* __restrict__ C, const int2* __restrict__ top2,
    const int2* __restrict__ posmap, const float2* __restrict__ gwv,
    const float* __restrict__ rnd, float* __restrict__ out)
{
  __shared__ __align__(16) float sxu[4][2][64];
  int tid = threadIdx.x;
  int lane = tid & 63;
  int w = tid >> 6;
  int b = blockIdx.x * 4 + w;                   // grid 2048*4 == B exactly
  int2 t2 = top2[b];
  t2.x &= 7; t2.y &= 7;
  int2 pm = posmap[b];
  pm.x = min(max(pm.x, 0), NPOS - 1);
  pm.y = min(max(pm.y, 0), NPOS - 1);
  float2 gw = gwv[b];
  float rv = rnd[b];

  sxu[w][0][lane] = xunP[(size_t)pm.x * H + lane];
  sxu[w][1][lane] = xunP[(size_t)pm.y * H + lane];

  const float4* C04 = (const float4*)(C + (size_t)pm.x * NCHUNK);
  const float4* C14 = (const float4*)(C + (size_t)pm.y * NCHUNK);
  float c0[NCHUNK], c1[NCHUNK];
#pragma unroll
  for (int q = 0; q < 4; ++q) {
    float4 v0 = C04[q], v1 = C14[q];
    c0[q*4+0]=v0.x; c0[q*4+1]=v0.y; c0[q*4+2]=v0.z; c0[q*4+3]=v0.w;
    c1[q*4+0]=v1.x; c1[q*4+1]=v1.y; c1[q*4+2]=v1.z; c1[q*4+3]=v1.w;
  }
  float S0 = 0.f, S1 = 0.f;
#pragma unroll
  for (int j = 0; j < NCHUNK; ++j) { S0 += c0[j]; S1 += c1[j]; }
  float a0 = gw.x / S0, a1 = gw.y / S1;
  int cstar = -1; float prefix = 0.f; float run = 0.f;
#pragma unroll
  for (int j = 0; j < NCHUNK; ++j) {
    float nrun = run + (c0[j] * a0 + c1[j] * a1);
    if (cstar < 0 && nrun > rv) { cstar = j; prefix = run; }
    run = nrun;
  }
  float rtgt = rv;
  if (cstar < 0) { cstar = 0; prefix = 0.f; rtgt = -1.0f; }

  __syncthreads();                              // sxu visible (no divergence)

  const float4* E0 = (const float4*)(evnN + ((size_t)t2.x * 1024 + cstar * CHUNK_E + lane) * H);
  const float4* E1 = (const float4*)(evnN + ((size_t)t2.y * 1024 + cstar * CHUNK_E + lane) * H);
  const float4* x0 = (const float4*)&sxu[w][0][0];
  const float4* x1 = (const float4*)&sxu[w][1][0];
  float d0 = 0.f, d1 = 0.f;
#pragma unroll
  for (int q = 0; q < 16; ++q) {                // same h order as before
    float4 e0 = E0[q], e1 = E1[q];
    float4 w0 = x0[q], w1 = x1[q];
    d0 = fmaf(e0.x, w0.x, d0); d0 = fmaf(e0.y, w0.y, d0);
    d0 = fmaf(e0.z, w0.z, d0); d0 = fmaf(e0.w, w0.w, d0);
    d1 = fmaf(e1.x, w1.x, d1); d1 = fmaf(e1.y, w1.y, d1);
    d1 = fmaf(e1.z, w1.z, d1); d1 = fmaf(e1.w, w1.w, d1);
  }
  float rea = __expf(d0) * a0 + __expf(d1) * a1;
  float sc = rea;
#pragma unroll
  for (int d = 1; d < 64; d <<= 1) {
    float o = __shfl_up(sc, d);
    if (lane >= d) sc += o;
  }
  float cum = prefix + sc;
  unsigned long long m2 = __ballot(cum > rtgt);
  int estar = (m2 == 0ull) ? 63 : (int)__builtin_ctzll(m2);
  float p = __shfl(rea, estar);
  if (lane == 0) {
    int sel = cstar * CHUNK_E + estar;
    out[b]     = (float)sel;
    out[B + b] = logf(p);
  }
}

// ---------------------------------------------------------------------------
extern "C" void kernel_launch(void* const* d_in, const int* in_sizes, int n_in,
                              void* d_out, int out_size, void* d_ws, size_t ws_size,
                              hipStream_t stream)
{
  (void)in_sizes; (void)n_in; (void)out_size; (void)ws_size;
  const float* x      = (const float*)d_in[0];
  const float* re     = (const float*)d_in[1];
  const float* rnd    = (const float*)d_in[2];
  const float* gate_w = (const float*)d_in[3];
  const float* gate_b = (const float*)d_in[4];
  const float* Uw     = (const float*)d_in[5];
  const float* Ub     = (const float*)d_in[6];
  const float* Vw     = (const float*)d_in[7];
  const float* Vb     = (const float*)d_in[8];
  char* ws = (char*)d_ws;
  int*    counts  = (int*)(ws + WS_CNT);
  int*    cursors = (int*)(ws + WS_CUR);
  float*  ps      = (float*)(ws + WS_PS);
  int*    offs    = (int*)(ws + WS_OFFS);
  int2*   top2    = (int2*)(ws + WS_TOP2);
  float2* gwv     = (float2*)(ws + WS_GW);
  int2*   posmap  = (int2*)(ws + WS_POSM);
  int*    list    = (int*)(ws + WS_LIST);
  float*  evnT    = (float*)(ws + WS_EVN);
  float*  xunP    = (float*)(ws + WS_XUN);
  float*  Cc      = (float*)(ws + WS_C);
  float*  evnN    = (float*)(ws + WS_EVNN);
  float* out = (float*)d_out;

  hipMemsetAsync(ws, 0, 128, stream);
  k_gate    <<<256,  256, 0, stream>>>(x, gate_w, gate_b, top2, gwv, counts, ps);
  k_scatter <<<32,   256, 0, stream>>>(top2, counts, ps, cursors, list, posmap, offs, out + 2 * B);
  k_projgemm<<<400,  256, 0, stream>>>(re, x, Vw, Uw, Vb, Ub, list, counts, offs, evnT, evnN, xunP);
  k_pass1   <<<4096, 256, 0, stream>>>(evnT, xunP, counts, offs, Cc);
  k_pass2   <<<2048, 256, 0, stream>>>(evnN, xunP, Cc, top2, posmap, gwv, rnd, out);
}

// Round 2
// 182.596 us; speedup vs baseline: 1.1968x; 1.1968x over previous
//
#include <hip/hip_runtime.h>
#include <math.h>

// Problem constants
#define B 8192
#define E 1024
#define D 384
#define H 64
#define R 8
#define NCHUNK 16
#define CHUNK_E 64
#define NPOS 17408          // 16384 + 8*128 per-router pad-to-128

// ws byte offsets (total ~9 MB; ws is 256 MiB per harness fill)
#define WS_CNT    0u          // int[8]  counts (atomic)
#define WS_CUR    32u         // int[8]  cursors (atomic)
#define WS_PS     64u         // float[8] prob sums (atomic)
#define WS_OFFS   96u         // int[8]  padded segment bases
#define WS_TOP2   256u        // int2[B]
#define WS_GW     65792u      // float2[B]
#define WS_POSM   131328u     // int2[B]
#define WS_LIST   196864u     // int[NPOS]
#define WS_EVN    266496u     // float[8*16*64*64] evnC[r][chunk][h][e'] (2 MB)
#define WS_XUN    2363648u    // float[NPOS*64]    xunP[pos][h]
#define WS_C      6820096u    // float[NPOS*16]    C[pos][chunk]

// ---------------- gate: lane = (sample, router); LDS-transposed gate_w -----
__global__ __launch_bounds__(256) void k_gate(
    const float* __restrict__ x, const float* __restrict__ gate_w,
    const float* __restrict__ gate_b, int2* __restrict__ top2,
    float2* __restrict__ gwv, int* __restrict__ counts, float* __restrict__ ps)
{
  __shared__ __align__(16) float gwT[R * 388];
  __shared__ float psl[R];
  __shared__ int   cl[R];
  int tid = threadIdx.x;
  for (int idx = tid; idx < D * R; idx += 256) {
    int k = idx >> 3, r = idx & 7;
    gwT[r * 388 + k] = gate_w[idx];
  }
  if (tid < R) { psl[tid] = 0.f; cl[tid] = 0; }
  __syncthreads();

  int l = tid & 63;
  int r = tid & 7;
  int b = blockIdx.x * 32 + (tid >> 3);
  float acc = gate_b[r];
  const float4* x4 = (const float4*)(x + (size_t)b * D);
  const float*  gr = gwT + r * 388;
#pragma unroll 4
  for (int q = 0; q < 96; ++q) {
    float4 xv = x4[q];
    float4 gv = *(const float4*)&gr[q * 4];
    acc = fmaf(xv.x, gv.x, acc);
    acc = fmaf(xv.y, gv.y, acc);
    acc = fmaf(xv.z, gv.z, acc);
    acc = fmaf(xv.w, gv.w, acc);
  }
  float lv[R];
#pragma unroll
  for (int rr = 0; rr < R; ++rr) lv[rr] = __shfl(acc, (l & ~7) + rr);
  int i0 = 0; float v0 = lv[0];
#pragma unroll
  for (int rr = 1; rr < R; ++rr) if (lv[rr] > v0) { v0 = lv[rr]; i0 = rr; }
  int i1 = (i0 == 0) ? 1 : 0; float v1 = lv[i1];
#pragma unroll
  for (int rr = 0; rr < R; ++rr)
    if (rr != i0 && lv[rr] > v1) { v1 = lv[rr]; i1 = rr; }
  float se = 0.f;
#pragma unroll
  for (int rr = 0; rr < R; ++rr) se += expf(lv[rr] - v0);
  float p = expf(acc - v0) / se;
  if (r == 0) {
    float e10 = expf(v1 - v0);
    top2[b] = make_int2(i0, i1);
    gwv[b]  = make_float2(1.f / (1.f + e10), e10 / (1.f + e10));
  }
  float pa = p;
  int   ca = (r == i0 ? 1 : 0) + (r == i1 ? 1 : 0);
#pragma unroll
  for (int m = 8; m < 64; m <<= 1) {
    pa += __shfl_xor(pa, m);
    ca += __shfl_xor(ca, m);
  }
  if (l < 8) { atomicAdd(&psl[r], pa); atomicAdd(&cl[r], ca); }
  __syncthreads();
  if (tid < R) { atomicAdd(&ps[tid], psl[tid]); atomicAdd(&counts[tid], cl[tid]); }
}

// ---------------- scatter: per-router lists (pad-128 bases) + aux + offs ---
__global__ __launch_bounds__(256) void k_scatter(
    const int2* __restrict__ top2, const int* __restrict__ counts,
    const float* __restrict__ ps, int* __restrict__ cursors,
    int* __restrict__ list, int2* __restrict__ posmap,
    int* __restrict__ offs_g, float* __restrict__ out_aux)
{
  __shared__ int lc[R];
  __shared__ int lbase[R];
  __shared__ int offs[R];
  int tid = threadIdx.x;
  if (tid < R) lc[tid] = 0;
  __syncthreads();
  if (tid == 0) {
    int o = 0;
    for (int r2 = 0; r2 < R; ++r2) { offs[r2] = o; o += (min(counts[r2], B) + 127) & ~127; }
  }
  __syncthreads();
  int b = min(blockIdx.x * 256 + tid, B - 1);
  int2 t = top2[b];
  t.x &= 7; t.y &= 7;
  int p0 = atomicAdd(&lc[t.x], 1);
  int p1 = atomicAdd(&lc[t.y], 1);
  __syncthreads();
  if (tid < R) lbase[tid] = atomicAdd(&cursors[tid], lc[tid]);
  __syncthreads();
  int i0 = min(offs[t.x] + lbase[t.x] + p0, NPOS - 1);
  int i1 = min(offs[t.y] + lbase[t.y] + p1, NPOS - 1);
  list[i0] = b * 2 + 0;
  list[i1] = b * 2 + 1;
  posmap[b] = make_int2(i0, i1);
  if (blockIdx.x == 0 && tid == 0) {
    float s = 0.f;
    for (int r2 = 0; r2 < R; ++r2) {
      s += (ps[r2] / (float)B) * ((float)min(counts[r2], B) / (float)B);
      offs_g[r2] = offs[r2];
    }
    out_aux[0] = (float)R * s * 0.05f;
  }
}

// ---------------- projgemm: fused full-K GEMM + bias + l2norm + writeout ---
// 256 threads; tile 64 rows x 64 h (full H); 4x4/thread; 6 k-stages of 64.
// grid 400 = 128 evn tiles + 272 xun tiles (pad-128 segs).
// Epilogue: row L2-norm via 16-lane shfl_xor reduce; writes
//   evn: evnC[r][chunk][h][e'] (chunk-contiguous 16 KB, via LDS transpose)
//   xun: xunP[pos][h]          (direct f4)
__global__ __launch_bounds__(256) void k_projgemm(
    const float* __restrict__ re, const float* __restrict__ x,
    const float* __restrict__ Vw, const float* __restrict__ Uw,
    const float* __restrict__ Vb, const float* __restrict__ Ub,
    const int* __restrict__ list, const int* __restrict__ counts,
    const int* __restrict__ offs, float* __restrict__ evnC,
    float* __restrict__ xunP)
{
  __shared__ __align__(16) float lds[8192];
  float* At = lds;            // [k][row] 64x64
  float* Wt = lds + 4096;     // [k][h]   64x64
  int tid = threadIdx.x;
  int tile = blockIdx.x;
  int rowg0 = tile * 64;

  int srow = tid & 63, kq = tid >> 6;           // staging roles
  const float* Wsrc;
  const float* arow;
  int r = 0;
  bool isE = (tile < 128);
  if (isE) {
    r = rowg0 >> 10;
    Wsrc = Vw + (size_t)r * (D * H);
    arow = re + (size_t)((rowg0 & 1023) + srow) * D;
  } else {
    int pos0 = rowg0 - 8192;
    int tot = offs[R - 1] + ((min(counts[R - 1], B) + 127) & ~127);
    if (pos0 >= tot) return;
    for (int rr = 0; rr < R; ++rr) if (pos0 >= offs[rr]) r = rr;
    Wsrc = Uw + (size_t)r * (D * H);
    int gl = list[min(pos0 + srow, NPOS - 1)];
    gl = min(max(gl, 0), 2 * B - 1);
    arow = x + (size_t)(gl >> 1) * D;
  }

  int tr = tid >> 4, tc = tid & 15;             // compute roles: 16 x 16
  float acc[4][4];
#pragma unroll
  for (int i = 0; i < 4; ++i)
#pragma unroll
    for (int j = 0; j < 4; ++j) acc[i][j] = 0.f;

  for (int kt = 0; kt < 6; ++kt) {
    int kb = kt * 64;
    __syncthreads();
#pragma unroll
    for (int q = 0; q < 4; ++q) {               // A: [row][k] -> At[k][row]
      float4 v = *(const float4*)&arow[kb + (kq + 4 * q) * 4];
      int k0 = (kq + 4 * q) * 4;
      At[(k0 + 0) * 64 + srow] = v.x;
      At[(k0 + 1) * 64 + srow] = v.y;
      At[(k0 + 2) * 64 + srow] = v.z;
      At[(k0 + 3) * 64 + srow] = v.w;
    }
#pragma unroll
    for (int q = 0; q < 4; ++q) {               // W: direct [k][h]
      int idx = tid + 256 * q;
      int k = idx >> 4, h4 = idx & 15;
      *(float4*)&Wt[k * 64 + h4 * 4] = *(const float4*)&Wsrc[(size_t)(kb + k) * H + h4 * 4];
    }
    __syncthreads();
#pragma unroll 8
    for (int k = 0; k < 64; ++k) {
      float4 a4 = *(const float4*)&At[k * 64 + tr * 4];
      float4 w4 = *(const float4*)&Wt[k * 64 + tc * 4];
      const float* ap = (const float*)&a4;
      const float* wp = (const float*)&w4;
#pragma unroll
      for (int i = 0; i < 4; ++i)
#pragma unroll
        for (int j = 0; j < 4; ++j) acc[i][j] = fmaf(ap[i], wp[j], acc[i][j]);
    }
  }

  // ---- epilogue: bias + row L2-norm (row = tr*4+i, its 64 h live on 16 tc lanes)
  const float* bsrc = (isE ? Vb : Ub) + r * H + tc * 4;
  float4 bv = *(const float4*)bsrc;
  float vv[4][4];
#pragma unroll
  for (int i = 0; i < 4; ++i) {
    vv[i][0] = acc[i][0] + bv.x;
    vv[i][1] = acc[i][1] + bv.y;
    vv[i][2] = acc[i][2] + bv.z;
    vv[i][3] = acc[i][3] + bv.w;
    float ss = vv[i][0] * vv[i][0] + vv[i][1] * vv[i][1]
             + vv[i][2] * vv[i][2] + vv[i][3] * vv[i][3];
#pragma unroll
    for (int m = 1; m < 16; m <<= 1) ss += __shfl_xor(ss, m);
    float dn = fmaxf(sqrtf(ss), 1e-12f);
    vv[i][0] /= dn; vv[i][1] /= dn; vv[i][2] /= dn; vv[i][3] /= dn;
  }

  if (!isE) {
    int pos0 = rowg0 - 8192;
#pragma unroll
    for (int i = 0; i < 4; ++i) {
      float4 o;
      o.x = vv[i][0]; o.y = vv[i][1]; o.z = vv[i][2]; o.w = vv[i][3];
      *(float4*)&xunP[(size_t)(pos0 + tr * 4 + i) * H + tc * 4] = o;
    }
    return;
  }

  // evn: this tile's 64 e-rows == exactly one chunk; transpose in LDS, then
  // write the 16 KB [h][e'] block fully contiguous/coalesced.
  int ebase = rowg0 & 1023;
  int cidx = ebase >> 6;
  __syncthreads();                              // all FMA reads of At/Wt done
#pragma unroll
  for (int i = 0; i < 4; ++i)                   // transpose: T[h*66 + e']
#pragma unroll
    for (int j = 0; j < 4; ++j)
      lds[(tc * 4 + j) * 66 + tr * 4 + i] = vv[i][j];
  __syncthreads();
  float* dst = evnC + (size_t)(r * NCHUNK + cidx) * 64 * 64;
#pragma unroll
  for (int q = 0; q < 4; ++q) {
    int idx = tid + 256 * q;
    int h = idx >> 4, f4 = idx & 15;
    float4 o;
    o.x = lds[h * 66 + f4 * 4 + 0];
    o.y = lds[h * 66 + f4 * 4 + 1];
    o.z = lds[h * 66 + f4 * 4 + 2];
    o.w = lds[h * 66 + f4 * 4 + 3];
    *(float4*)&dst[h * 64 + f4 * 4] = o;
  }
}

// ---------------- pass1: scores GEMM -> __expf -> chunk sums ---------------
// tile 128 pos x 128 e; 8x8/thread; 32-k double-stage => LDS 32 KB.
// Reads evnC (chunk-major): e-tile of 128 = chunks {2*et, 2*et+1}.
__global__ __launch_bounds__(256) void k_pass1(
    const float* __restrict__ evnC, const float* __restrict__ xunP,
    const int* __restrict__ counts, const int* __restrict__ offs,
    float* __restrict__ C)
{
  __shared__ __align__(16) float Xt[32 * 128];
  __shared__ __align__(16) float Et[32 * 128];
  int tid = threadIdx.x;
  int bid = blockIdx.x;
  int et    = bid & 7;
  int stile = (bid >> 3) & 63;
  int r     = bid >> 9;
  int cnt = min(counts[r], B);
  if (cnt <= 0 || stile * 128 >= cnt) return;
  int off = offs[r] + stile * 128;
  int n = min(128, cnt - stile * 128);

  int sg = tid >> 4, egr = tid & 15;
  float acc[8][8];
#pragma unroll
  for (int i = 0; i < 8; ++i)
#pragma unroll
    for (int j = 0; j < 8; ++j) acc[i][j] = 0.f;

  int srow = tid >> 1, shalf = tid & 1;
  int src = min(srow, n - 1);
  const float4* xsrc = (const float4*)(xunP + (size_t)(off + src) * H);

  for (int kst = 0; kst < 2; ++kst) {
    __syncthreads();
    {  // Xt: [pos][h] -> [h-local][s]
#pragma unroll
      for (int q = 0; q < 4; ++q) {
        float4 v = xsrc[kst * 8 + shalf * 4 + q];
        int hb = shalf * 16 + q * 4;
        Xt[(hb + 0) * 128 + srow] = v.x;
        Xt[(hb + 1) * 128 + srow] = v.y;
        Xt[(hb + 2) * 128 + srow] = v.z;
        Xt[(hb + 3) * 128 + srow] = v.w;
      }
    }
    {  // Et: evnC chunks {2et, 2et+1}, rows h = kst*32 .. +32
#pragma unroll
      for (int q = 0; q < 4; ++q) {
        int idx = tid + 256 * q;
        int h = idx >> 5, e4 = idx & 31;
        int cc = et * 2 + (e4 >> 4);
        *(float4*)&Et[h * 128 + e4 * 4] =
            *(const float4*)(evnC + ((size_t)(r * NCHUNK + cc) * 64 + kst * 32 + h) * 64
                             + (e4 & 15) * 4);
      }
    }
    __syncthreads();
#pragma unroll 4
    for (int k = 0; k < 32; ++k) {
      float4 xa = *(const float4*)&Xt[k * 128 + sg * 4];
      float4 xb = *(const float4*)&Xt[k * 128 + 64 + sg * 4];
      float4 ea = *(const float4*)&Et[k * 128 + egr * 4];
      float4 eb = *(const float4*)&Et[k * 128 + 64 + egr * 4];
      const float* pa = (const float*)&xa;
      const float* pb = (const float*)&xb;
      const float* qa = (const float*)&ea;
      const float* qb = (const float*)&eb;
#pragma unroll
      for (int i = 0; i < 4; ++i)
#pragma unroll
        for (int j = 0; j < 4; ++j) {
          acc[i][j]         = fmaf(pa[i], qa[j], acc[i][j]);
          acc[i][j + 4]     = fmaf(pa[i], qb[j], acc[i][j + 4]);
          acc[i + 4][j]     = fmaf(pb[i], qa[j], acc[i + 4][j]);
          acc[i + 4][j + 4] = fmaf(pb[i], qb[j], acc[i + 4][j + 4]);
        }
    }
  }

#pragma unroll
  for (int i = 0; i < 8; ++i) {
    float cA = __expf(acc[i][0]) + __expf(acc[i][1]) + __expf(acc[i][2]) + __expf(acc[i][3]);
    float cB = __expf(acc[i][4]) + __expf(acc[i][5]) + __expf(acc[i][6]) + __expf(acc[i][7]);
#pragma unroll
    for (int m = 1; m < 16; m <<= 1) {
      cA += __shfl_xor(cA, m);
      cB += __shfl_xor(cB, m);
    }
    int s = (i < 4) ? (sg * 4 + i) : (64 + sg * 4 + i - 4);
    if (egr == 0 && s < n) {
      C[(size_t)(off + s) * NCHUNK + et * 2]     = cA;
      C[(size_t)(off + s) * NCHUNK + et * 2 + 1] = cB;
    }
  }
}

// ---------------- pass2: chunk-level inverse-CDF, recompute 1 chunk --------
// Chunk block is 16 KB contiguous: wave reads it as 16 coalesced 1KB f4 loads
// (each 64B line requested exactly once). Lane l covers e' = (l&15)*4..+3,
// h-residue l>>4; h-reduce via 2 shfl_xor; 16-lane scan for the CDF.
__global__ __launch_bounds__(256) void k_pass2(
    const float* __restrict__ evnC, const float* __restrict__ xunP,
    const float* __restrict__ C, const int2* __restrict__ top2,
    const int2* __restrict__ posmap, const float2* __restrict__ gwv,
    const float* __restrict__ rnd, float* __restrict__ out)
{
  __shared__ __align__(16) float sxu[4][2][64];
  int tid = threadIdx.x;
  int lane = tid & 63;
  int w = tid >> 6;
  int b = blockIdx.x * 4 + w;                   // grid 2048*4 == B exactly
  int2 t2 = top2[b];
  t2.x &= 7; t2.y &= 7;
  int2 pm = posmap[b];
  pm.x = min(max(pm.x, 0), NPOS - 1);
  pm.y = min(max(pm.y, 0), NPOS - 1);
  float2 gw = gwv[b];
  float rv = rnd[b];

  sxu[w][0][lane] = xunP[(size_t)pm.x * H + lane];
  sxu[w][1][lane] = xunP[(size_t)pm.y * H + lane];

  const float4* C04 = (const float4*)(C + (size_t)pm.x * NCHUNK);
  const float4* C14 = (const float4*)(C + (size_t)pm.y * NCHUNK);
  float c0[NCHUNK], c1[NCHUNK];
#pragma unroll
  for (int q = 0; q < 4; ++q) {
    float4 v0 = C04[q], v1 = C14[q];
    c0[q*4+0]=v0.x; c0[q*4+1]=v0.y; c0[q*4+2]=v0.z; c0[q*4+3]=v0.w;
    c1[q*4+0]=v1.x; c1[q*4+1]=v1.y; c1[q*4+2]=v1.z; c1[q*4+3]=v1.w;
  }
  float S0 = 0.f, S1 = 0.f;
#pragma unroll
  for (int j = 0; j < NCHUNK; ++j) { S0 += c0[j]; S1 += c1[j]; }
  float a0 = gw.x / S0, a1 = gw.y / S1;
  int cstar = -1; float prefix = 0.f; float run = 0.f;
#pragma unroll
  for (int j = 0; j < NCHUNK; ++j) {
    float nrun = run + (c0[j] * a0 + c1[j] * a1);
    if (cstar < 0 && nrun > rv) { cstar = j; prefix = run; }
    run = nrun;
  }
  float rtgt = rv;
  if (cstar < 0) { cstar = 0; prefix = 0.f; rtgt = -1.0f; }

  __syncthreads();                              // sxu visible (no divergence)

  const float4* E0 = (const float4*)(evnC + (size_t)(t2.x * NCHUNK + cstar) * 64 * 64);
  const float4* E1 = (const float4*)(evnC + (size_t)(t2.y * NCHUNK + cstar) * 64 * 64);
  const float* x0 = &sxu[w][0][0];
  const float* x1 = &sxu[w][1][0];
  int hq = lane >> 4;
  float d0[4] = {0.f, 0.f, 0.f, 0.f};
  float d1[4] = {0.f, 0.f, 0.f, 0.f};
#pragma unroll
  for (int q = 0; q < 16; ++q) {                // f4 at linear q*256 + lane*4:
    float4 e0 = E0[q * 64 + lane];              //   h = q*4 + hq, e' = (lane&15)*4
    float4 e1 = E1[q * 64 + lane];
    float w0 = x0[q * 4 + hq];
    float w1 = x1[q * 4 + hq];
    d0[0] = fmaf(e0.x, w0, d0[0]); d0[1] = fmaf(e0.y, w0, d0[1]);
    d0[2] = fmaf(e0.z, w0, d0[2]); d0[3] = fmaf(e0.w, w0, d0[3]);
    d1[0] = fmaf(e1.x, w1, d1[0]); d1[1] = fmaf(e1.y, w1, d1[1]);
    d1[2] = fmaf(e1.z, w1, d1[2]); d1[3] = fmaf(e1.w, w1, d1[3]);
  }
#pragma unroll
  for (int j = 0; j < 4; ++j) {                 // combine h-residues
    d0[j] += __shfl_xor(d0[j], 16);
    d0[j] += __shfl_xor(d0[j], 32);
    d1[j] += __shfl_xor(d1[j], 16);
    d1[j] += __shfl_xor(d1[j], 32);
  }
  float rea[4], inc[4];
  float trun = 0.f;
#pragma unroll
  for (int j = 0; j < 4; ++j) {
    rea[j] = __expf(d0[j]) * a0 + __expf(d1[j]) * a1;
    trun += rea[j];
    inc[j] = trun;
  }
  float sc = trun;                              // width-16 inclusive scan
#pragma unroll
  for (int d = 1; d < 16; d <<= 1) {
    float o = __shfl_up(sc, d, 16);
    if ((lane & 15) >= d) sc += o;
  }
  float base = prefix + (sc - trun);            // exclusive prefix for this lane
  unsigned long long m2 = __ballot(base + inc[3] > rtgt) & 0xFFFFull;
  int lstar = (m2 == 0ull) ? 15 : (int)__builtin_ctzll(m2);
  int jloc = 3;
  if (base + inc[2] > rtgt) jloc = 2;
  if (base + inc[1] > rtgt) jloc = 1;
  if (base + inc[0] > rtgt) jloc = 0;
  float pl = (jloc == 0) ? rea[0] : (jloc == 1) ? rea[1] : (jloc == 2) ? rea[2] : rea[3];
  int   js = __shfl(jloc, lstar);
  float p  = __shfl(pl, lstar);
  if (lane == 0) {
    int sel = cstar * CHUNK_E + lstar * 4 + js;
    out[b]     = (float)sel;
    out[B + b] = logf(p);
  }
}

// ---------------------------------------------------------------------------
extern "C" void kernel_launch(void* const* d_in, const int* in_sizes, int n_in,
                              void* d_out, int out_size, void* d_ws, size_t ws_size,
                              hipStream_t stream)
{
  (void)in_sizes; (void)n_in; (void)out_size; (void)ws_size;
  const float* x      = (const float*)d_in[0];
  const float* re     = (const float*)d_in[1];
  const float* rnd    = (const float*)d_in[2];
  const float* gate_w = (const float*)d_in[3];
  const float* gate_b = (const float*)d_in[4];
  const float* Uw     = (const float*)d_in[5];
  const float* Ub     = (const float*)d_in[6];
  const float* Vw     = (const float*)d_in[7];
  const float* Vb     = (const float*)d_in[8];
  char* ws = (char*)d_ws;
  int*    counts  = (int*)(ws + WS_CNT);
  int*    cursors = (int*)(ws + WS_CUR);
  float*  ps      = (float*)(ws + WS_PS);
  int*    offs    = (int*)(ws + WS_OFFS);
  int2*   top2    = (int2*)(ws + WS_TOP2);
  float2* gwv     = (float2*)(ws + WS_GW);
  int2*   posmap  = (int2*)(ws + WS_POSM);
  int*    list    = (int*)(ws + WS_LIST);
  float*  evnC    = (float*)(ws + WS_EVN);
  float*  xunP    = (float*)(ws + WS_XUN);
  float*  Cc      = (float*)(ws + WS_C);
  float* out = (float*)d_out;

  hipMemsetAsync(ws, 0, 128, stream);
  k_gate    <<<256,  256, 0, stream>>>(x, gate_w, gate_b, top2, gwv, counts, ps);
  k_scatter <<<32,   256, 0, stream>>>(top2, counts, ps, cursors, list, posmap, offs, out + 2 * B);
  k_projgemm<<<400,  256, 0, stream>>>(re, x, Vw, Uw, Vb, Ub, list, counts, offs, evnC, xunP);
  k_pass1   <<<4096, 256, 0, stream>>>(evnC, xunP, counts, offs, Cc);
  k_pass2   <<<2048, 256, 0, stream>>>(evnC, xunP, Cc, top2, posmap, gwv, rnd, out);
}

// Round 3
// 176.331 us; speedup vs baseline: 1.2394x; 1.0355x over previous
//
#include <hip/hip_runtime.h>
#include <math.h>

// Problem constants
#define B 8192
#define E 1024
#define D 384
#define H 64
#define R 8
#define NCHUNK 16
#define CHUNK_E 64
#define NPOS 17408          // 16384 + 8*128 per-router pad-to-128

// ws byte offsets (total ~9 MB; ws is 256 MiB per harness fill)
#define WS_CNT    0u          // int[8]  counts (atomic)
#define WS_CUR    32u         // int[8]  cursors (atomic)
#define WS_PS     64u         // float[8] prob sums (atomic)
#define WS_OFFS   96u         // int[8]  padded segment bases
#define WS_TOP2   256u        // int2[B]
#define WS_GW     65792u      // float2[B]
#define WS_POSM   131328u     // int2[B]
#define WS_LIST   196864u     // int[NPOS]
#define WS_EVN    266496u     // float[8*16*64*64] evnC[r][chunk][h][e'] (2 MB)
#define WS_XUN    2363648u    // float[NPOS*64]    xunP[pos][h]
#define WS_C      6820096u    // float[NPOS*16]    C[pos][chunk]

// ---------------- gate: lane = (sample, router); LDS-transposed gate_w -----
__global__ __launch_bounds__(256) void k_gate(
    const float* __restrict__ x, const float* __restrict__ gate_w,
    const float* __restrict__ gate_b, int2* __restrict__ top2,
    float2* __restrict__ gwv, int* __restrict__ counts, float* __restrict__ ps)
{
  __shared__ __align__(16) float gwT[R * 388];
  __shared__ float psl[R];
  __shared__ int   cl[R];
  int tid = threadIdx.x;
  for (int idx = tid; idx < D * R; idx += 256) {
    int k = idx >> 3, r = idx & 7;
    gwT[r * 388 + k] = gate_w[idx];
  }
  if (tid < R) { psl[tid] = 0.f; cl[tid] = 0; }
  __syncthreads();

  int l = tid & 63;
  int r = tid & 7;
  int b = blockIdx.x * 32 + (tid >> 3);
  float acc = gate_b[r];
  const float4* x4 = (const float4*)(x + (size_t)b * D);
  const float*  gr = gwT + r * 388;
#pragma unroll 4
  for (int q = 0; q < 96; ++q) {
    float4 xv = x4[q];
    float4 gv = *(const float4*)&gr[q * 4];
    acc = fmaf(xv.x, gv.x, acc);
    acc = fmaf(xv.y, gv.y, acc);
    acc = fmaf(xv.z, gv.z, acc);
    acc = fmaf(xv.w, gv.w, acc);
  }
  float lv[R];
#pragma unroll
  for (int rr = 0; rr < R; ++rr) lv[rr] = __shfl(acc, (l & ~7) + rr);
  int i0 = 0; float v0 = lv[0];
#pragma unroll
  for (int rr = 1; rr < R; ++rr) if (lv[rr] > v0) { v0 = lv[rr]; i0 = rr; }
  int i1 = (i0 == 0) ? 1 : 0; float v1 = lv[i1];
#pragma unroll
  for (int rr = 0; rr < R; ++rr)
    if (rr != i0 && lv[rr] > v1) { v1 = lv[rr]; i1 = rr; }
  float se = 0.f;
#pragma unroll
  for (int rr = 0; rr < R; ++rr) se += expf(lv[rr] - v0);
  float p = expf(acc - v0) / se;
  if (r == 0) {
    float e10 = expf(v1 - v0);
    top2[b] = make_int2(i0, i1);
    gwv[b]  = make_float2(1.f / (1.f + e10), e10 / (1.f + e10));
  }
  float pa = p;
  int   ca = (r == i0 ? 1 : 0) + (r == i1 ? 1 : 0);
#pragma unroll
  for (int m = 8; m < 64; m <<= 1) {
    pa += __shfl_xor(pa, m);
    ca += __shfl_xor(ca, m);
  }
  if (l < 8) { atomicAdd(&psl[r], pa); atomicAdd(&cl[r], ca); }
  __syncthreads();
  if (tid < R) { atomicAdd(&ps[tid], psl[tid]); atomicAdd(&counts[tid], cl[tid]); }
}

// ---------------- scatter: per-router lists (pad-128 bases) + aux + offs ---
__global__ __launch_bounds__(256) void k_scatter(
    const int2* __restrict__ top2, const int* __restrict__ counts,
    const float* __restrict__ ps, int* __restrict__ cursors,
    int* __restrict__ list, int2* __restrict__ posmap,
    int* __restrict__ offs_g, float* __restrict__ out_aux)
{
  __shared__ int lc[R];
  __shared__ int lbase[R];
  __shared__ int offs[R];
  int tid = threadIdx.x;
  if (tid < R) lc[tid] = 0;
  __syncthreads();
  if (tid == 0) {
    int o = 0;
    for (int r2 = 0; r2 < R; ++r2) { offs[r2] = o; o += (min(counts[r2], B) + 127) & ~127; }
  }
  __syncthreads();
  int b = min(blockIdx.x * 256 + tid, B - 1);
  int2 t = top2[b];
  t.x &= 7; t.y &= 7;
  int p0 = atomicAdd(&lc[t.x], 1);
  int p1 = atomicAdd(&lc[t.y], 1);
  __syncthreads();
  if (tid < R) lbase[tid] = atomicAdd(&cursors[tid], lc[tid]);
  __syncthreads();
  int i0 = min(offs[t.x] + lbase[t.x] + p0, NPOS - 1);
  int i1 = min(offs[t.y] + lbase[t.y] + p1, NPOS - 1);
  list[i0] = b * 2 + 0;
  list[i1] = b * 2 + 1;
  posmap[b] = make_int2(i0, i1);
  if (blockIdx.x == 0 && tid == 0) {
    float s = 0.f;
    for (int r2 = 0; r2 < R; ++r2) {
      s += (ps[r2] / (float)B) * ((float)min(counts[r2], B) / (float)B);
      offs_g[r2] = offs[r2];
    }
    out_aux[0] = (float)R * s * 0.05f;
  }
}

// ---------------- projgemm: fused full-K GEMM + bias + l2norm + writeout ---
// 256 threads; tile 64 rows x 64 h (full H); 4x4/thread; 6 k-stages of 64.
// DOUBLE-BUFFERED (T14 async-split): stage t+1's global loads issue into
// registers before stage t's FMA loop; ds_write into the alternate LDS
// buffer after compute; ONE barrier per stage. FP accumulation order is
// unchanged vs the single-buffered version (bitwise-identical outputs).
// grid 400 = 128 evn tiles + 272 xun tiles (pad-128 segs). LDS 64 KB.
__global__ __launch_bounds__(256) void k_projgemm(
    const float* __restrict__ re, const float* __restrict__ x,
    const float* __restrict__ Vw, const float* __restrict__ Uw,
    const float* __restrict__ Vb, const float* __restrict__ Ub,
    const int* __restrict__ list, const int* __restrict__ counts,
    const int* __restrict__ offs, float* __restrict__ evnC,
    float* __restrict__ xunP)
{
  __shared__ __align__(16) float At[2][4096];   // [buf][k][row]
  __shared__ __align__(16) float Wt[2][4096];   // [buf][k][h]
  int tid = threadIdx.x;
  int tile = blockIdx.x;
  int rowg0 = tile * 64;

  int srow = tid & 63, kq = tid >> 6;           // staging roles
  const float* Wsrc;
  const float* arow;
  int r = 0;
  bool isE = (tile < 128);
  if (isE) {
    r = rowg0 >> 10;
    Wsrc = Vw + (size_t)r * (D * H);
    arow = re + (size_t)((rowg0 & 1023) + srow) * D;
  } else {
    int pos0 = rowg0 - 8192;
    int tot = offs[R - 1] + ((min(counts[R - 1], B) + 127) & ~127);
    if (pos0 >= tot) return;
    for (int rr = 0; rr < R; ++rr) if (pos0 >= offs[rr]) r = rr;
    Wsrc = Uw + (size_t)r * (D * H);
    int gl = list[min(pos0 + srow, NPOS - 1)];
    gl = min(max(gl, 0), 2 * B - 1);
    arow = x + (size_t)(gl >> 1) * D;
  }

  int tr = tid >> 4, tc = tid & 15;             // compute roles: 16 x 16
  float acc[4][4];
#pragma unroll
  for (int i = 0; i < 4; ++i)
#pragma unroll
    for (int j = 0; j < 4; ++j) acc[i][j] = 0.f;

  float4 va[4], vw[4];                          // in-flight stage registers

  // --- prologue: stage 0 ---
#pragma unroll
  for (int q = 0; q < 4; ++q)
    va[q] = *(const float4*)&arow[(kq + 4 * q) * 4];
#pragma unroll
  for (int q = 0; q < 4; ++q) {
    int idx = tid + 256 * q;
    int k = idx >> 4, h4 = idx & 15;
    vw[q] = *(const float4*)&Wsrc[(size_t)k * H + h4 * 4];
  }
#pragma unroll
  for (int q = 0; q < 4; ++q) {
    int k0 = (kq + 4 * q) * 4;
    At[0][(k0 + 0) * 64 + srow] = va[q].x;
    At[0][(k0 + 1) * 64 + srow] = va[q].y;
    At[0][(k0 + 2) * 64 + srow] = va[q].z;
    At[0][(k0 + 3) * 64 + srow] = va[q].w;
  }
#pragma unroll
  for (int q = 0; q < 4; ++q) {
    int idx = tid + 256 * q;
    int k = idx >> 4, h4 = idx & 15;
    *(float4*)&Wt[0][k * 64 + h4 * 4] = vw[q];
  }
  __syncthreads();

  for (int kt = 0; kt < 6; ++kt) {
    int cur = kt & 1;
    if (kt < 5) {                               // issue next stage's loads NOW
      int kb = (kt + 1) * 64;
#pragma unroll
      for (int q = 0; q < 4; ++q)
        va[q] = *(const float4*)&arow[kb + (kq + 4 * q) * 4];
#pragma unroll
      for (int q = 0; q < 4; ++q) {
        int idx = tid + 256 * q;
        int k = idx >> 4, h4 = idx & 15;
        vw[q] = *(const float4*)&Wsrc[(size_t)(kb + k) * H + h4 * 4];
      }
    }
#pragma unroll 8
    for (int k = 0; k < 64; ++k) {              // compute current stage
      float4 a4 = *(const float4*)&At[cur][k * 64 + tr * 4];
      float4 w4 = *(const float4*)&Wt[cur][k * 64 + tc * 4];
      const float* ap = (const float*)&a4;
      const float* wp = (const float*)&w4;
#pragma unroll
      for (int i = 0; i < 4; ++i)
#pragma unroll
        for (int j = 0; j < 4; ++j) acc[i][j] = fmaf(ap[i], wp[j], acc[i][j]);
    }
    if (kt < 5) {                               // write next stage to alt buf
      int nxt = cur ^ 1;
#pragma unroll
      for (int q = 0; q < 4; ++q) {
        int k0 = (kq + 4 * q) * 4;
        At[nxt][(k0 + 0) * 64 + srow] = va[q].x;
        At[nxt][(k0 + 1) * 64 + srow] = va[q].y;
        At[nxt][(k0 + 2) * 64 + srow] = va[q].z;
        At[nxt][(k0 + 3) * 64 + srow] = va[q].w;
      }
#pragma unroll
      for (int q = 0; q < 4; ++q) {
        int idx = tid + 256 * q;
        int k = idx >> 4, h4 = idx & 15;
        *(float4*)&Wt[nxt][k * 64 + h4 * 4] = vw[q];
      }
    }
    __syncthreads();
  }

  // ---- epilogue: bias + row L2-norm (row = tr*4+i, its 64 h live on 16 tc lanes)
  const float* bsrc = (isE ? Vb : Ub) + r * H + tc * 4;
  float4 bv = *(const float4*)bsrc;
  float vv[4][4];
#pragma unroll
  for (int i = 0; i < 4; ++i) {
    vv[i][0] = acc[i][0] + bv.x;
    vv[i][1] = acc[i][1] + bv.y;
    vv[i][2] = acc[i][2] + bv.z;
    vv[i][3] = acc[i][3] + bv.w;
    float ss = vv[i][0] * vv[i][0] + vv[i][1] * vv[i][1]
             + vv[i][2] * vv[i][2] + vv[i][3] * vv[i][3];
#pragma unroll
    for (int m = 1; m < 16; m <<= 1) ss += __shfl_xor(ss, m);
    float dn = fmaxf(sqrtf(ss), 1e-12f);
    vv[i][0] /= dn; vv[i][1] /= dn; vv[i][2] /= dn; vv[i][3] /= dn;
  }

  if (!isE) {
    int pos0 = rowg0 - 8192;
#pragma unroll
    for (int i = 0; i < 4; ++i) {
      float4 o;
      o.x = vv[i][0]; o.y = vv[i][1]; o.z = vv[i][2]; o.w = vv[i][3];
      *(float4*)&xunP[(size_t)(pos0 + tr * 4 + i) * H + tc * 4] = o;
    }
    return;
  }

  // evn: this tile's 64 e-rows == exactly one chunk; transpose in LDS, then
  // write the 16 KB [h][e'] block fully contiguous/coalesced.
  float* scratch = &At[0][0];                   // 64*66 = 4224 <= 8192 floats
  int ebase = rowg0 & 1023;
  int cidx = ebase >> 6;
  // final loop iteration ended with __syncthreads(): all FMA reads done
#pragma unroll
  for (int i = 0; i < 4; ++i)                   // transpose: T[h*66 + e']
#pragma unroll
    for (int j = 0; j < 4; ++j)
      scratch[(tc * 4 + j) * 66 + tr * 4 + i] = vv[i][j];
  __syncthreads();
  float* dst = evnC + (size_t)(r * NCHUNK + cidx) * 64 * 64;
#pragma unroll
  for (int q = 0; q < 4; ++q) {
    int idx = tid + 256 * q;
    int h = idx >> 4, f4 = idx & 15;
    float4 o;
    o.x = scratch[h * 66 + f4 * 4 + 0];
    o.y = scratch[h * 66 + f4 * 4 + 1];
    o.z = scratch[h * 66 + f4 * 4 + 2];
    o.w = scratch[h * 66 + f4 * 4 + 3];
    *(float4*)&dst[h * 64 + f4 * 4] = o;
  }
}

// ---------------- pass1: scores GEMM -> __expf -> chunk sums ---------------
// tile 128 pos x 128 e; 8x8/thread; 32-k double-stage => LDS 32 KB.
// Reads evnC (chunk-major): e-tile of 128 = chunks {2*et, 2*et+1}.
__global__ __launch_bounds__(256) void k_pass1(
    const float* __restrict__ evnC, const float* __restrict__ xunP,
    const int* __restrict__ counts, const int* __restrict__ offs,
    float* __restrict__ C)
{
  __shared__ __align__(16) float Xt[32 * 128];
  __shared__ __align__(16) float Et[32 * 128];
  int tid = threadIdx.x;
  int bid = blockIdx.x;
  int et    = bid & 7;
  int stile = (bid >> 3) & 63;
  int r     = bid >> 9;
  int cnt = min(counts[r], B);
  if (cnt <= 0 || stile * 128 >= cnt) return;
  int off = offs[r] + stile * 128;
  int n = min(128, cnt - stile * 128);

  int sg = tid >> 4, egr = tid & 15;
  float acc[8][8];
#pragma unroll
  for (int i = 0; i < 8; ++i)
#pragma unroll
    for (int j = 0; j < 8; ++j) acc[i][j] = 0.f;

  int srow = tid >> 1, shalf = tid & 1;
  int src = min(srow, n - 1);
  const float4* xsrc = (const float4*)(xunP + (size_t)(off + src) * H);

  for (int kst = 0; kst < 2; ++kst) {
    __syncthreads();
    {  // Xt: [pos][h] -> [h-local][s]
#pragma unroll
      for (int q = 0; q < 4; ++q) {
        float4 v = xsrc[kst * 8 + shalf * 4 + q];
        int hb = shalf * 16 + q * 4;
        Xt[(hb + 0) * 128 + srow] = v.x;
        Xt[(hb + 1) * 128 + srow] = v.y;
        Xt[(hb + 2) * 128 + srow] = v.z;
        Xt[(hb + 3) * 128 + srow] = v.w;
      }
    }
    {  // Et: evnC chunks {2et, 2et+1}, rows h = kst*32 .. +32
#pragma unroll
      for (int q = 0; q < 4; ++q) {
        int idx = tid + 256 * q;
        int h = idx >> 5, e4 = idx & 31;
        int cc = et * 2 + (e4 >> 4);
        *(float4*)&Et[h * 128 + e4 * 4] =
            *(const float4*)(evnC + ((size_t)(r * NCHUNK + cc) * 64 + kst * 32 + h) * 64
                             + (e4 & 15) * 4);
      }
    }
    __syncthreads();
#pragma unroll 4
    for (int k = 0; k < 32; ++k) {
      float4 xa = *(const float4*)&Xt[k * 128 + sg * 4];
      float4 xb = *(const float4*)&Xt[k * 128 + 64 + sg * 4];
      float4 ea = *(const float4*)&Et[k * 128 + egr * 4];
      float4 eb = *(const float4*)&Et[k * 128 + 64 + egr * 4];
      const float* pa = (const float*)&xa;
      const float* pb = (const float*)&xb;
      const float* qa = (const float*)&ea;
      const float* qb = (const float*)&eb;
#pragma unroll
      for (int i = 0; i < 4; ++i)
#pragma unroll
        for (int j = 0; j < 4; ++j) {
          acc[i][j]         = fmaf(pa[i], qa[j], acc[i][j]);
          acc[i][j + 4]     = fmaf(pa[i], qb[j], acc[i][j + 4]);
          acc[i + 4][j]     = fmaf(pb[i], qa[j], acc[i + 4][j]);
          acc[i + 4][j + 4] = fmaf(pb[i], qb[j], acc[i + 4][j + 4]);
        }
    }
  }

#pragma unroll
  for (int i = 0; i < 8; ++i) {
    float cA = __expf(acc[i][0]) + __expf(acc[i][1]) + __expf(acc[i][2]) + __expf(acc[i][3]);
    float cB = __expf(acc[i][4]) + __expf(acc[i][5]) + __expf(acc[i][6]) + __expf(acc[i][7]);
#pragma unroll
    for (int m = 1; m < 16; m <<= 1) {
      cA += __shfl_xor(cA, m);
      cB += __shfl_xor(cB, m);
    }
    int s = (i < 4) ? (sg * 4 + i) : (64 + sg * 4 + i - 4);
    if (egr == 0 && s < n) {
      C[(size_t)(off + s) * NCHUNK + et * 2]     = cA;
      C[(size_t)(off + s) * NCHUNK + et * 2 + 1] = cB;
    }
  }
}

// ---------------- pass2: chunk-level inverse-CDF, recompute 1 chunk --------
// Chunk block is 16 KB contiguous: wave reads it as 16 coalesced 1KB f4 loads
// (each 64B line requested exactly once). Lane l covers e' = (l&15)*4..+3,
// h-residue l>>4; h-reduce via 2 shfl_xor; 16-lane scan for the CDF.
__global__ __launch_bounds__(256) void k_pass2(
    const float* __restrict__ evnC, const float* __restrict__ xunP,
    const float* __restrict__ C, const int2* __restrict__ top2,
    const int2* __restrict__ posmap, const float2* __restrict__ gwv,
    const float* __restrict__ rnd, float* __restrict__ out)
{
  __shared__ __align__(16) float sxu[4][2][64];
  int tid = threadIdx.x;
  int lane = tid & 63;
  int w = tid >> 6;
  int b = blockIdx.x * 4 + w;                   // grid 2048*4 == B exactly
  int2 t2 = top2[b];
  t2.x &= 7; t2.y &= 7;
  int2 pm = posmap[b];
  pm.x = min(max(pm.x, 0), NPOS - 1);
  pm.y = min(max(pm.y, 0), NPOS - 1);
  float2 gw = gwv[b];
  float rv = rnd[b];

  sxu[w][0][lane] = xunP[(size_t)pm.x * H + lane];
  sxu[w][1][lane] = xunP[(size_t)pm.y * H + lane];

  const float4* C04 = (const float4*)(C + (size_t)pm.x * NCHUNK);
  const float4* C14 = (const float4*)(C + (size_t)pm.y * NCHUNK);
  float c0[NCHUNK], c1[NCHUNK];
#pragma unroll
  for (int q = 0; q < 4; ++q) {
    float4 v0 = C04[q], v1 = C14[q];
    c0[q*4+0]=v0.x; c0[q*4+1]=v0.y; c0[q*4+2]=v0.z; c0[q*4+3]=v0.w;
    c1[q*4+0]=v1.x; c1[q*4+1]=v1.y; c1[q*4+2]=v1.z; c1[q*4+3]=v1.w;
  }
  float S0 = 0.f, S1 = 0.f;
#pragma unroll
  for (int j = 0; j < NCHUNK; ++j) { S0 += c0[j]; S1 += c1[j]; }
  float a0 = gw.x / S0, a1 = gw.y / S1;
  int cstar = -1; float prefix = 0.f; float run = 0.f;
#pragma unroll
  for (int j = 0; j < NCHUNK; ++j) {
    float nrun = run + (c0[j] * a0 + c1[j] * a1);
    if (cstar < 0 && nrun > rv) { cstar = j; prefix = run; }
    run = nrun;
  }
  float rtgt = rv;
  if (cstar < 0) { cstar = 0; prefix = 0.f; rtgt = -1.0f; }

  __syncthreads();                              // sxu visible (no divergence)

  const float4* E0 = (const float4*)(evnC + (size_t)(t2.x * NCHUNK + cstar) * 64 * 64);
  const float4* E1 = (const float4*)(evnC + (size_t)(t2.y * NCHUNK + cstar) * 64 * 64);
  const float* x0 = &sxu[w][0][0];
  const float* x1 = &sxu[w][1][0];
  int hq = lane >> 4;
  float d0[4] = {0.f, 0.f, 0.f, 0.f};
  float d1[4] = {0.f, 0.f, 0.f, 0.f};
#pragma unroll
  for (int q = 0; q < 16; ++q) {                // f4 at linear q*256 + lane*4:
    float4 e0 = E0[q * 64 + lane];              //   h = q*4 + hq, e' = (lane&15)*4
    float4 e1 = E1[q * 64 + lane];
    float w0 = x0[q * 4 + hq];
    float w1 = x1[q * 4 + hq];
    d0[0] = fmaf(e0.x, w0, d0[0]); d0[1] = fmaf(e0.y, w0, d0[1]);
    d0[2] = fmaf(e0.z, w0, d0[2]); d0[3] = fmaf(e0.w, w0, d0[3]);
    d1[0] = fmaf(e1.x, w1, d1[0]); d1[1] = fmaf(e1.y, w1, d1[1]);
    d1[2] = fmaf(e1.z, w1, d1[2]); d1[3] = fmaf(e1.w, w1, d1[3]);
  }
#pragma unroll
  for (int j = 0; j < 4; ++j) {                 // combine h-residues
    d0[j] += __shfl_xor(d0[j], 16);
    d0[j] += __shfl_xor(d0[j], 32);
    d1[j] += __shfl_xor(d1[j], 16);
    d1[j] += __shfl_xor(d1[j], 32);
  }
  float rea[4], inc[4];
  float trun = 0.f;
#pragma unroll
  for (int j = 0; j < 4; ++j) {
    rea[j] = __expf(d0[j]) * a0 + __expf(d1[j]) * a1;
    trun += rea[j];
    inc[j] = trun;
  }
  float sc = trun;                              // width-16 inclusive scan
#pragma unroll
  for (int d = 1; d < 16; d <<= 1) {
    float o = __shfl_up(sc, d, 16);
    if ((lane & 15) >= d) sc += o;
  }
  float base = prefix + (sc - trun);            // exclusive prefix for this lane
  unsigned long long m2 = __ballot(base + inc[3] > rtgt) & 0xFFFFull;
  int lstar = (m2 == 0ull) ? 15 : (int)__builtin_ctzll(m2);
  int jloc = 3;
  if (base + inc[2] > rtgt) jloc = 2;
  if (base + inc[1] > rtgt) jloc = 1;
  if (base + inc[0] > rtgt) jloc = 0;
  float pl = (jloc == 0) ? rea[0] : (jloc == 1) ? rea[1] : (jloc == 2) ? rea[2] : rea[3];
  int   js = __shfl(jloc, lstar);
  float p  = __shfl(pl, lstar);
  if (lane == 0) {
    int sel = cstar * CHUNK_E + lstar * 4 + js;
    out[b]     = (float)sel;
    out[B + b] = logf(p);
  }
}

// ---------------------------------------------------------------------------
extern "C" void kernel_launch(void* const* d_in, const int* in_sizes, int n_in,
                              void* d_out, int out_size, void* d_ws, size_t ws_size,
                              hipStream_t stream)
{
  (void)in_sizes; (void)n_in; (void)out_size; (void)ws_size;
  const float* x      = (const float*)d_in[0];
  const float* re     = (const float*)d_in[1];
  const float* rnd    = (const float*)d_in[2];
  const float* gate_w = (const float*)d_in[3];
  const float* gate_b = (const float*)d_in[4];
  const float* Uw     = (const float*)d_in[5];
  const float* Ub     = (const float*)d_in[6];
  const float* Vw     = (const float*)d_in[7];
  const float* Vb     = (const float*)d_in[8];
  char* ws = (char*)d_ws;
  int*    counts  = (int*)(ws + WS_CNT);
  int*    cursors = (int*)(ws + WS_CUR);
  float*  ps      = (float*)(ws + WS_PS);
  int*    offs    = (int*)(ws + WS_OFFS);
  int2*   top2    = (int2*)(ws + WS_TOP2);
  float2* gwv     = (float2*)(ws + WS_GW);
  int2*   posmap  = (int2*)(ws + WS_POSM);
  int*    list    = (int*)(ws + WS_LIST);
  float*  evnC    = (float*)(ws + WS_EVN);
  float*  xunP    = (float*)(ws + WS_XUN);
  float*  Cc      = (float*)(ws + WS_C);
  float* out = (float*)d_out;

  hipMemsetAsync(ws, 0, 128, stream);
  k_gate    <<<256,  256, 0, stream>>>(x, gate_w, gate_b, top2, gwv, counts, ps);
  k_scatter <<<32,   256, 0, stream>>>(top2, counts, ps, cursors, list, posmap, offs, out + 2 * B);
  k_projgemm<<<400,  256, 0, stream>>>(re, x, Vw, Uw, Vb, Ub, list, counts, offs, evnC, xunP);
  k_pass1   <<<4096, 256, 0, stream>>>(evnC, xunP, counts, offs, Cc);
  k_pass2   <<<2048, 256, 0, stream>>>(evnC, xunP, Cc, top2, posmap, gwv, rnd, out);
}

// Round 4
// 171.450 us; speedup vs baseline: 1.2746x; 1.0285x over previous
//
#include <hip/hip_runtime.h>
#include <math.h>

// Problem constants
#define B 8192
#define E 1024
#define D 384
#define H 64
#define R 8
#define NCHUNK 16
#define CHUNK_E 64
#define NPOS 17408          // 16384 + 8*128 per-router pad-to-128

// ws byte offsets (total ~9 MB; ws is 256 MiB per harness fill)
#define WS_CNT    0u          // int[8]  counts (atomic)
#define WS_CUR    32u         // int[8]  cursors (atomic)
#define WS_PS     64u         // float[8] prob sums (atomic)
#define WS_OFFS   96u         // int[8]  padded segment bases
#define WS_TOP2   256u        // int2[B]
#define WS_GW     65792u      // float2[B]
#define WS_POSM   131328u     // int2[B]
#define WS_LIST   196864u     // int[NPOS]
#define WS_EVN    266496u     // float[8*16*64*64] evnC[r][chunk][h][e'] (2 MB)
#define WS_XUN    2363648u    // float[NPOS*64]    xunP[pos][h]
#define WS_C      6820096u    // float[NPOS*16]    C[pos][chunk]

// ---------------- gate: lane = (sample, router); LDS-transposed gate_w -----
__global__ __launch_bounds__(256) void k_gate(
    const float* __restrict__ x, const float* __restrict__ gate_w,
    const float* __restrict__ gate_b, int2* __restrict__ top2,
    float2* __restrict__ gwv, int* __restrict__ counts, float* __restrict__ ps)
{
  __shared__ __align__(16) float gwT[R * 388];
  __shared__ float psl[R];
  __shared__ int   cl[R];
  int tid = threadIdx.x;
  for (int idx = tid; idx < D * R; idx += 256) {
    int k = idx >> 3, r = idx & 7;
    gwT[r * 388 + k] = gate_w[idx];
  }
  if (tid < R) { psl[tid] = 0.f; cl[tid] = 0; }
  __syncthreads();

  int l = tid & 63;
  int r = tid & 7;
  int b = blockIdx.x * 32 + (tid >> 3);
  float acc = gate_b[r];
  const float4* x4 = (const float4*)(x + (size_t)b * D);
  const float*  gr = gwT + r * 388;
#pragma unroll 4
  for (int q = 0; q < 96; ++q) {
    float4 xv = x4[q];
    float4 gv = *(const float4*)&gr[q * 4];
    acc = fmaf(xv.x, gv.x, acc);
    acc = fmaf(xv.y, gv.y, acc);
    acc = fmaf(xv.z, gv.z, acc);
    acc = fmaf(xv.w, gv.w, acc);
  }
  float lv[R];
#pragma unroll
  for (int rr = 0; rr < R; ++rr) lv[rr] = __shfl(acc, (l & ~7) + rr);
  int i0 = 0; float v0 = lv[0];
#pragma unroll
  for (int rr = 1; rr < R; ++rr) if (lv[rr] > v0) { v0 = lv[rr]; i0 = rr; }
  int i1 = (i0 == 0) ? 1 : 0; float v1 = lv[i1];
#pragma unroll
  for (int rr = 0; rr < R; ++rr)
    if (rr != i0 && lv[rr] > v1) { v1 = lv[rr]; i1 = rr; }
  float se = 0.f;
#pragma unroll
  for (int rr = 0; rr < R; ++rr) se += expf(lv[rr] - v0);
  float p = expf(acc - v0) / se;
  if (r == 0) {
    float e10 = expf(v1 - v0);
    top2[b] = make_int2(i0, i1);
    gwv[b]  = make_float2(1.f / (1.f + e10), e10 / (1.f + e10));
  }
  float pa = p;
  int   ca = (r == i0 ? 1 : 0) + (r == i1 ? 1 : 0);
#pragma unroll
  for (int m = 8; m < 64; m <<= 1) {
    pa += __shfl_xor(pa, m);
    ca += __shfl_xor(ca, m);
  }
  if (l < 8) { atomicAdd(&psl[r], pa); atomicAdd(&cl[r], ca); }
  __syncthreads();
  if (tid < R) { atomicAdd(&ps[tid], psl[tid]); atomicAdd(&counts[tid], cl[tid]); }
}

// ---------------- scatter: per-router lists (pad-128 bases) + aux + offs ---
__global__ __launch_bounds__(256) void k_scatter(
    const int2* __restrict__ top2, const int* __restrict__ counts,
    const float* __restrict__ ps, int* __restrict__ cursors,
    int* __restrict__ list, int2* __restrict__ posmap,
    int* __restrict__ offs_g, float* __restrict__ out_aux)
{
  __shared__ int lc[R];
  __shared__ int lbase[R];
  __shared__ int offs[R];
  int tid = threadIdx.x;
  if (tid < R) lc[tid] = 0;
  __syncthreads();
  if (tid == 0) {
    int o = 0;
    for (int r2 = 0; r2 < R; ++r2) { offs[r2] = o; o += (min(counts[r2], B) + 127) & ~127; }
  }
  __syncthreads();
  int b = min(blockIdx.x * 256 + tid, B - 1);
  int2 t = top2[b];
  t.x &= 7; t.y &= 7;
  int p0 = atomicAdd(&lc[t.x], 1);
  int p1 = atomicAdd(&lc[t.y], 1);
  __syncthreads();
  if (tid < R) lbase[tid] = atomicAdd(&cursors[tid], lc[tid]);
  __syncthreads();
  int i0 = min(offs[t.x] + lbase[t.x] + p0, NPOS - 1);
  int i1 = min(offs[t.y] + lbase[t.y] + p1, NPOS - 1);
  list[i0] = b * 2 + 0;
  list[i1] = b * 2 + 1;
  posmap[b] = make_int2(i0, i1);
  if (blockIdx.x == 0 && tid == 0) {
    float s = 0.f;
    for (int r2 = 0; r2 < R; ++r2) {
      s += (ps[r2] / (float)B) * ((float)min(counts[r2], B) / (float)B);
      offs_g[r2] = offs[r2];
    }
    out_aux[0] = (float)R * s * 0.05f;
  }
}

// ---------------- projgemm: fused full-K GEMM + bias + l2norm + writeout ---
// Tile 128 rows x 64 h; 256 threads = 16 rowgroups x 16 colgroups; 8x4/lane.
// Per lane per k: a8 (2x b128) + w4 (1x b128) = 3 LDS insts / 32 FMA
// (1.5x better FMA:LDS ratio than the old 4x4). 6 k-stages of 64,
// double-buffered with register prefetch; one barrier per stage.
// grid 200 = 64 evn tiles + <=136 xun tiles (pad-128 segs, 128-aligned).
// FP accumulation order per output is unchanged (k sequential 0..383,
// same fmaf grouping, same 16-lane norm tree) -> outputs bitwise identical.
__global__ __launch_bounds__(256) void k_projgemm(
    const float* __restrict__ re, const float* __restrict__ x,
    const float* __restrict__ Vw, const float* __restrict__ Uw,
    const float* __restrict__ Vb, const float* __restrict__ Ub,
    const int* __restrict__ list, const int* __restrict__ counts,
    const int* __restrict__ offs, float* __restrict__ evnC,
    float* __restrict__ xunP)
{
  __shared__ __align__(16) float At[2][64 * 128];  // [buf][k][row]  64 KB
  __shared__ __align__(16) float Wt[2][64 * 64];   // [buf][k][h]    32 KB
  int tid = threadIdx.x;
  int tile = blockIdx.x;
  int rowg0 = tile * 128;

  int srow = tid & 127, kh = tid >> 7;          // A staging: 2 threads/row
  const float* Wsrc;
  const float* arow;
  int r = 0;
  bool isE = (tile < 64);
  if (isE) {
    r = rowg0 >> 10;
    Wsrc = Vw + (size_t)r * (D * H);
    arow = re + (size_t)((rowg0 & 1023) + srow) * D;
  } else {
    int pos0 = rowg0 - 8192;
    int tot = offs[R - 1] + ((min(counts[R - 1], B) + 127) & ~127);
    if (pos0 >= tot) return;
    for (int rr = 0; rr < R; ++rr) if (pos0 >= offs[rr]) r = rr;
    Wsrc = Uw + (size_t)r * (D * H);
    int gl = list[min(pos0 + srow, NPOS - 1)];
    gl = min(max(gl, 0), 2 * B - 1);
    arow = x + (size_t)(gl >> 1) * D;
  }
  const float4* arow4 = (const float4*)arow;
  const float4* Wsrc4 = (const float4*)Wsrc;

  int rg = tid >> 4, cg = tid & 15;             // compute roles: 16 x 16
  float acc[8][4];
#pragma unroll
  for (int i = 0; i < 8; ++i)
#pragma unroll
    for (int j = 0; j < 4; ++j) acc[i][j] = 0.f;

  float4 va[8], vw[4];                          // in-flight stage registers

  // --- prologue: stage 0 ---
#pragma unroll
  for (int q = 0; q < 8; ++q)
    va[q] = arow4[kh * 8 + q];                  // k = kh*32 + q*4 .. +3
#pragma unroll
  for (int q = 0; q < 4; ++q) {
    int idx = tid + 256 * q;
    int k = idx >> 4, h4 = idx & 15;
    vw[q] = Wsrc4[(size_t)k * 16 + h4];
  }
#pragma unroll
  for (int q = 0; q < 8; ++q) {
    int k0 = kh * 32 + q * 4;
    At[0][(k0 + 0) * 128 + srow] = va[q].x;
    At[0][(k0 + 1) * 128 + srow] = va[q].y;
    At[0][(k0 + 2) * 128 + srow] = va[q].z;
    At[0][(k0 + 3) * 128 + srow] = va[q].w;
  }
#pragma unroll
  for (int q = 0; q < 4; ++q) {
    int idx = tid + 256 * q;
    int k = idx >> 4, h4 = idx & 15;
    *(float4*)&Wt[0][k * 64 + h4 * 4] = vw[q];
  }
  __syncthreads();

  for (int kt = 0; kt < 6; ++kt) {
    int cur = kt & 1;
    if (kt < 5) {                               // issue next stage's loads NOW
      int kb4 = (kt + 1) * 16;                  // f4 index of stage base
#pragma unroll
      for (int q = 0; q < 8; ++q)
        va[q] = arow4[kb4 + kh * 8 + q];
#pragma unroll
      for (int q = 0; q < 4; ++q) {
        int idx = tid + 256 * q;
        int k = idx >> 4, h4 = idx & 15;
        vw[q] = Wsrc4[(size_t)((kt + 1) * 64 + k) * 16 + h4];
      }
    }
    {
      const float4* At4 = (const float4*)&At[cur][0];
      const float4* Wt4 = (const float4*)&Wt[cur][0];
#pragma unroll 8
      for (int k = 0; k < 64; ++k) {            // compute current stage
        float4 a0 = At4[(k * 128 + rg * 8) >> 2];
        float4 a1 = At4[(k * 128 + rg * 8 + 4) >> 2];
        float4 w4 = Wt4[(k * 64 + cg * 4) >> 2];
        const float* a0p = (const float*)&a0;
        const float* a1p = (const float*)&a1;
        const float* wp  = (const float*)&w4;
#pragma unroll
        for (int i = 0; i < 4; ++i)
#pragma unroll
          for (int j = 0; j < 4; ++j) {
            acc[i][j]     = fmaf(a0p[i], wp[j], acc[i][j]);
            acc[i + 4][j] = fmaf(a1p[i], wp[j], acc[i + 4][j]);
          }
      }
    }
    if (kt < 5) {                               // write next stage to alt buf
      int nxt = cur ^ 1;
#pragma unroll
      for (int q = 0; q < 8; ++q) {
        int k0 = kh * 32 + q * 4;
        At[nxt][(k0 + 0) * 128 + srow] = va[q].x;
        At[nxt][(k0 + 1) * 128 + srow] = va[q].y;
        At[nxt][(k0 + 2) * 128 + srow] = va[q].z;
        At[nxt][(k0 + 3) * 128 + srow] = va[q].w;
      }
#pragma unroll
      for (int q = 0; q < 4; ++q) {
        int idx = tid + 256 * q;
        int k = idx >> 4, h4 = idx & 15;
        *(float4*)&Wt[nxt][k * 64 + h4 * 4] = vw[q];
      }
    }
    __syncthreads();
  }

  // ---- epilogue: bias + row L2-norm (row = rg*8+i; its 64 h on 16 cg lanes)
  const float* bsrc = (isE ? Vb : Ub) + r * H + cg * 4;
  float4 bv = *(const float4*)bsrc;
#pragma unroll
  for (int i = 0; i < 8; ++i) {
    acc[i][0] += bv.x;
    acc[i][1] += bv.y;
    acc[i][2] += bv.z;
    acc[i][3] += bv.w;
    float ss = acc[i][0] * acc[i][0] + acc[i][1] * acc[i][1]
             + acc[i][2] * acc[i][2] + acc[i][3] * acc[i][3];
#pragma unroll
    for (int m = 1; m < 16; m <<= 1) ss += __shfl_xor(ss, m);
    float dn = fmaxf(sqrtf(ss), 1e-12f);
    acc[i][0] /= dn; acc[i][1] /= dn; acc[i][2] /= dn; acc[i][3] /= dn;
  }

  if (!isE) {
    int pos0 = rowg0 - 8192;
#pragma unroll
    for (int i = 0; i < 8; ++i) {
      float4 o;
      o.x = acc[i][0]; o.y = acc[i][1]; o.z = acc[i][2]; o.w = acc[i][3];
      *(float4*)&xunP[(size_t)(pos0 + rg * 8 + i) * H + cg * 4] = o;
    }
    return;
  }

  // evn: tile's 128 e-rows == two chunks; transpose via pad-133 LDS scratch,
  // then write two contiguous 16 KB [h][e'] blocks fully coalesced.
  float* scratch = &At[0][0];                   // 64*133 = 8512 floats < 16384
  int ebase = rowg0 & 1023;
  int cidx = ebase >> 6;
  // final loop iteration ended with __syncthreads(): all FMA reads done
#pragma unroll
  for (int i = 0; i < 8; ++i)                   // scratch[h*133 + e_local]
#pragma unroll
    for (int j = 0; j < 4; ++j)
      scratch[(cg * 4 + j) * 133 + rg * 8 + i] = acc[i][j];
  __syncthreads();
#pragma unroll
  for (int q = 0; q < 8; ++q) {
    int idx = tid + 256 * q;                    // 0..2047
    int eh  = idx >> 10;                        // which chunk half (0/1)
    int rem = idx & 1023;
    int h = rem >> 4, f4 = rem & 15;
    float4 o;
    o.x = scratch[h * 133 + eh * 64 + f4 * 4 + 0];
    o.y = scratch[h * 133 + eh * 64 + f4 * 4 + 1];
    o.z = scratch[h * 133 + eh * 64 + f4 * 4 + 2];
    o.w = scratch[h * 133 + eh * 64 + f4 * 4 + 3];
    float* dst = evnC + (size_t)(r * NCHUNK + cidx + eh) * 64 * 64;
    *(float4*)&dst[h * 64 + f4 * 4] = o;
  }
}

// ---------------- pass1: scores GEMM -> __expf -> chunk sums ---------------
// tile 128 pos x 128 e; 8x8/thread; 32-k double-stage => LDS 32 KB.
// Reads evnC (chunk-major): e-tile of 128 = chunks {2*et, 2*et+1}.
__global__ __launch_bounds__(256) void k_pass1(
    const float* __restrict__ evnC, const float* __restrict__ xunP,
    const int* __restrict__ counts, const int* __restrict__ offs,
    float* __restrict__ C)
{
  __shared__ __align__(16) float Xt[32 * 128];
  __shared__ __align__(16) float Et[32 * 128];
  int tid = threadIdx.x;
  int bid = blockIdx.x;
  int et    = bid & 7;
  int stile = (bid >> 3) & 63;
  int r     = bid >> 9;
  int cnt = min(counts[r], B);
  if (cnt <= 0 || stile * 128 >= cnt) return;
  int off = offs[r] + stile * 128;
  int n = min(128, cnt - stile * 128);

  int sg = tid >> 4, egr = tid & 15;
  float acc[8][8];
#pragma unroll
  for (int i = 0; i < 8; ++i)
#pragma unroll
    for (int j = 0; j < 8; ++j) acc[i][j] = 0.f;

  int srow = tid >> 1, shalf = tid & 1;
  int src = min(srow, n - 1);
  const float4* xsrc = (const float4*)(xunP + (size_t)(off + src) * H);

  for (int kst = 0; kst < 2; ++kst) {
    __syncthreads();
    {  // Xt: [pos][h] -> [h-local][s]
#pragma unroll
      for (int q = 0; q < 4; ++q) {
        float4 v = xsrc[kst * 8 + shalf * 4 + q];
        int hb = shalf * 16 + q * 4;
        Xt[(hb + 0) * 128 + srow] = v.x;
        Xt[(hb + 1) * 128 + srow] = v.y;
        Xt[(hb + 2) * 128 + srow] = v.z;
        Xt[(hb + 3) * 128 + srow] = v.w;
      }
    }
    {  // Et: evnC chunks {2et, 2et+1}, rows h = kst*32 .. +32
#pragma unroll
      for (int q = 0; q < 4; ++q) {
        int idx = tid + 256 * q;
        int h = idx >> 5, e4 = idx & 31;
        int cc = et * 2 + (e4 >> 4);
        *(float4*)&Et[h * 128 + e4 * 4] =
            *(const float4*)(evnC + ((size_t)(r * NCHUNK + cc) * 64 + kst * 32 + h) * 64
                             + (e4 & 15) * 4);
      }
    }
    __syncthreads();
#pragma unroll 4
    for (int k = 0; k < 32; ++k) {
      float4 xa = *(const float4*)&Xt[k * 128 + sg * 4];
      float4 xb = *(const float4*)&Xt[k * 128 + 64 + sg * 4];
      float4 ea = *(const float4*)&Et[k * 128 + egr * 4];
      float4 eb = *(const float4*)&Et[k * 128 + 64 + egr * 4];
      const float* pa = (const float*)&xa;
      const float* pb = (const float*)&xb;
      const float* qa = (const float*)&ea;
      const float* qb = (const float*)&eb;
#pragma unroll
      for (int i = 0; i < 4; ++i)
#pragma unroll
        for (int j = 0; j < 4; ++j) {
          acc[i][j]         = fmaf(pa[i], qa[j], acc[i][j]);
          acc[i][j + 4]     = fmaf(pa[i], qb[j], acc[i][j + 4]);
          acc[i + 4][j]     = fmaf(pb[i], qa[j], acc[i + 4][j]);
          acc[i + 4][j + 4] = fmaf(pb[i], qb[j], acc[i + 4][j + 4]);
        }
    }
  }

#pragma unroll
  for (int i = 0; i < 8; ++i) {
    float cA = __expf(acc[i][0]) + __expf(acc[i][1]) + __expf(acc[i][2]) + __expf(acc[i][3]);
    float cB = __expf(acc[i][4]) + __expf(acc[i][5]) + __expf(acc[i][6]) + __expf(acc[i][7]);
#pragma unroll
    for (int m = 1; m < 16; m <<= 1) {
      cA += __shfl_xor(cA, m);
      cB += __shfl_xor(cB, m);
    }
    int s = (i < 4) ? (sg * 4 + i) : (64 + sg * 4 + i - 4);
    if (egr == 0 && s < n) {
      C[(size_t)(off + s) * NCHUNK + et * 2]     = cA;
      C[(size_t)(off + s) * NCHUNK + et * 2 + 1] = cB;
    }
  }
}

// ---------------- pass2: chunk-level inverse-CDF, recompute 1 chunk --------
// Chunk block is 16 KB contiguous: wave reads it as 16 coalesced 1KB f4 loads
// (each 64B line requested exactly once). Lane l covers e' = (l&15)*4..+3,
// h-residue l>>4; h-reduce via 2 shfl_xor; 16-lane scan for the CDF.
__global__ __launch_bounds__(256) void k_pass2(
    const float* __restrict__ evnC, const float* __restrict__ xunP,
    const float* __restrict__ C, const int2* __restrict__ top2,
    const int2* __restrict__ posmap, const float2* __restrict__ gwv,
    const float* __restrict__ rnd, float* __restrict__ out)
{
  __shared__ __align__(16) float sxu[4][2][64];
  int tid = threadIdx.x;
  int lane = tid & 63;
  int w = tid >> 6;
  int b = blockIdx.x * 4 + w;                   // grid 2048*4 == B exactly
  int2 t2 = top2[b];
  t2.x &= 7; t2.y &= 7;
  int2 pm = posmap[b];
  pm.x = min(max(pm.x, 0), NPOS - 1);
  pm.y = min(max(pm.y, 0), NPOS - 1);
  float2 gw = gwv[b];
  float rv = rnd[b];

  sxu[w][0][lane] = xunP[(size_t)pm.x * H + lane];
  sxu[w][1][lane] = xunP[(size_t)pm.y * H + lane];

  const float4* C04 = (const float4*)(C + (size_t)pm.x * NCHUNK);
  const float4* C14 = (const float4*)(C + (size_t)pm.y * NCHUNK);
  float c0[NCHUNK], c1[NCHUNK];
#pragma unroll
  for (int q = 0; q < 4; ++q) {
    float4 v0 = C04[q], v1 = C14[q];
    c0[q*4+0]=v0.x; c0[q*4+1]=v0.y; c0[q*4+2]=v0.z; c0[q*4+3]=v0.w;
    c1[q*4+0]=v1.x; c1[q*4+1]=v1.y; c1[q*4+2]=v1.z; c1[q*4+3]=v1.w;
  }
  float S0 = 0.f, S1 = 0.f;
#pragma unroll
  for (int j = 0; j < NCHUNK; ++j) { S0 += c0[j]; S1 += c1[j]; }
  float a0 = gw.x / S0, a1 = gw.y / S1;
  int cstar = -1; float prefix = 0.f; float run = 0.f;
#pragma unroll
  for (int j = 0; j < NCHUNK; ++j) {
    float nrun = run + (c0[j] * a0 + c1[j] * a1);
    if (cstar < 0 && nrun > rv) { cstar = j; prefix = run; }
    run = nrun;
  }
  float rtgt = rv;
  if (cstar < 0) { cstar = 0; prefix = 0.f; rtgt = -1.0f; }

  __syncthreads();                              // sxu visible (no divergence)

  const float4* E0 = (const float4*)(evnC + (size_t)(t2.x * NCHUNK + cstar) * 64 * 64);
  const float4* E1 = (const float4*)(evnC + (size_t)(t2.y * NCHUNK + cstar) * 64 * 64);
  const float* x0 = &sxu[w][0][0];
  const float* x1 = &sxu[w][1][0];
  int hq = lane >> 4;
  float d0[4] = {0.f, 0.f, 0.f, 0.f};
  float d1[4] = {0.f, 0.f, 0.f, 0.f};
#pragma unroll
  for (int q = 0; q < 16; ++q) {                // f4 at linear q*256 + lane*4:
    float4 e0 = E0[q * 64 + lane];              //   h = q*4 + hq, e' = (lane&15)*4
    float4 e1 = E1[q * 64 + lane];
    float w0 = x0[q * 4 + hq];
    float w1 = x1[q * 4 + hq];
    d0[0] = fmaf(e0.x, w0, d0[0]); d0[1] = fmaf(e0.y, w0, d0[1]);
    d0[2] = fmaf(e0.z, w0, d0[2]); d0[3] = fmaf(e0.w, w0, d0[3]);
    d1[0] = fmaf(e1.x, w1, d1[0]); d1[1] = fmaf(e1.y, w1, d1[1]);
    d1[2] = fmaf(e1.z, w1, d1[2]); d1[3] = fmaf(e1.w, w1, d1[3]);
  }
#pragma unroll
  for (int j = 0; j < 4; ++j) {                 // combine h-residues
    d0[j] += __shfl_xor(d0[j], 16);
    d0[j] += __shfl_xor(d0[j], 32);
    d1[j] += __shfl_xor(d1[j], 16);
    d1[j] += __shfl_xor(d1[j], 32);
  }
  float rea[4], inc[4];
  float trun = 0.f;
#pragma unroll
  for (int j = 0; j < 4; ++j) {
    rea[j] = __expf(d0[j]) * a0 + __expf(d1[j]) * a1;
    trun += rea[j];
    inc[j] = trun;
  }
  float sc = trun;                              // width-16 inclusive scan
#pragma unroll
  for (int d = 1; d < 16; d <<= 1) {
    float o = __shfl_up(sc, d, 16);
    if ((lane & 15) >= d) sc += o;
  }
  float base = prefix + (sc - trun);            // exclusive prefix for this lane
  unsigned long long m2 = __ballot(base + inc[3] > rtgt) & 0xFFFFull;
  int lstar = (m2 == 0ull) ? 15 : (int)__builtin_ctzll(m2);
  int jloc = 3;
  if (base + inc[2] > rtgt) jloc = 2;
  if (base + inc[1] > rtgt) jloc = 1;
  if (base + inc[0] > rtgt) jloc = 0;
  float pl = (jloc == 0) ? rea[0] : (jloc == 1) ? rea[1] : (jloc == 2) ? rea[2] : rea[3];
  int   js = __shfl(jloc, lstar);
  float p  = __shfl(pl, lstar);
  if (lane == 0) {
    int sel = cstar * CHUNK_E + lstar * 4 + js;
    out[b]     = (float)sel;
    out[B + b] = logf(p);
  }
}

// ---------------------------------------------------------------------------
extern "C" void kernel_launch(void* const* d_in, const int* in_sizes, int n_in,
                              void* d_out, int out_size, void* d_ws, size_t ws_size,
                              hipStream_t stream)
{
  (void)in_sizes; (void)n_in; (void)out_size; (void)ws_size;
  const float* x      = (const float*)d_in[0];
  const float* re     = (const float*)d_in[1];
  const float* rnd    = (const float*)d_in[2];
  const float* gate_w = (const float*)d_in[3];
  const float* gate_b = (const float*)d_in[4];
  const float* Uw     = (const float*)d_in[5];
  const float* Ub     = (const float*)d_in[6];
  const float* Vw     = (const float*)d_in[7];
  const float* Vb     = (const float*)d_in[8];
  char* ws = (char*)d_ws;
  int*    counts  = (int*)(ws + WS_CNT);
  int*    cursors = (int*)(ws + WS_CUR);
  float*  ps      = (float*)(ws + WS_PS);
  int*    offs    = (int*)(ws + WS_OFFS);
  int2*   top2    = (int2*)(ws + WS_TOP2);
  float2* gwv     = (float2*)(ws + WS_GW);
  int2*   posmap  = (int2*)(ws + WS_POSM);
  int*    list    = (int*)(ws + WS_LIST);
  float*  evnC    = (float*)(ws + WS_EVN);
  float*  xunP    = (float*)(ws + WS_XUN);
  float*  Cc      = (float*)(ws + WS_C);
  float* out = (float*)d_out;

  hipMemsetAsync(ws, 0, 128, stream);
  k_gate    <<<256,  256, 0, stream>>>(x, gate_w, gate_b, top2, gwv, counts, ps);
  k_scatter <<<32,   256, 0, stream>>>(top2, counts, ps, cursors, list, posmap, offs, out + 2 * B);
  k_projgemm<<<200,  256, 0, stream>>>(re, x, Vw, Uw, Vb, Ub, list, counts, offs, evnC, xunP);
  k_pass1   <<<4096, 256, 0, stream>>>(evnC, xunP, counts, offs, Cc);
  k_pass2   <<<2048, 256, 0, stream>>>(evnC, xunP, Cc, top2, posmap, gwv, rnd, out);
}

// Round 5
// 171.205 us; speedup vs baseline: 1.2765x; 1.0014x over previous
//
#include <hip/hip_runtime.h>
#include <math.h>

// Problem constants
#define B 8192
#define E 1024
#define D 384
#define H 64
#define R 8
#define NCHUNK 16
#define CHUNK_E 64
#define NPOS 17408          // 16384 + 8*128 per-router pad-to-128

// ws byte offsets (total ~9 MB; ws is 256 MiB per harness fill)
#define WS_CNT    0u          // int[8]  counts (atomic)
#define WS_CUR    32u         // int[8]  cursors (atomic)
#define WS_PS     64u         // float[8] prob sums (atomic)
#define WS_OFFS   96u         // int[8]  padded segment bases
#define WS_TOP2   256u        // int2[B]
#define WS_GW     65792u      // float2[B]
#define WS_POSM   131328u     // int2[B]
#define WS_LIST   196864u     // int[NPOS]
#define WS_EVN    266496u     // float[8*16*64*64] evnC[r][chunk][h][e'] (2 MB)
#define WS_XUN    2363648u    // float[NPOS*64]    xunP[pos][h]
#define WS_C      6820096u    // float[NPOS*16]    C[pos][chunk]

// ---------------- gate: lane = (sample, router); LDS-transposed gate_w -----
__global__ __launch_bounds__(256) void k_gate(
    const float* __restrict__ x, const float* __restrict__ gate_w,
    const float* __restrict__ gate_b, int2* __restrict__ top2,
    float2* __restrict__ gwv, int* __restrict__ counts, float* __restrict__ ps)
{
  __shared__ __align__(16) float gwT[R * 388];
  __shared__ float psl[R];
  __shared__ int   cl[R];
  int tid = threadIdx.x;
  for (int idx = tid; idx < D * R; idx += 256) {
    int k = idx >> 3, r = idx & 7;
    gwT[r * 388 + k] = gate_w[idx];
  }
  if (tid < R) { psl[tid] = 0.f; cl[tid] = 0; }
  __syncthreads();

  int l = tid & 63;
  int r = tid & 7;
  int b = blockIdx.x * 32 + (tid >> 3);
  float acc = gate_b[r];
  const float4* x4 = (const float4*)(x + (size_t)b * D);
  const float*  gr = gwT + r * 388;
#pragma unroll 4
  for (int q = 0; q < 96; ++q) {
    float4 xv = x4[q];
    float4 gv = *(const float4*)&gr[q * 4];
    acc = fmaf(xv.x, gv.x, acc);
    acc = fmaf(xv.y, gv.y, acc);
    acc = fmaf(xv.z, gv.z, acc);
    acc = fmaf(xv.w, gv.w, acc);
  }
  float lv[R];
#pragma unroll
  for (int rr = 0; rr < R; ++rr) lv[rr] = __shfl(acc, (l & ~7) + rr);
  int i0 = 0; float v0 = lv[0];
#pragma unroll
  for (int rr = 1; rr < R; ++rr) if (lv[rr] > v0) { v0 = lv[rr]; i0 = rr; }
  int i1 = (i0 == 0) ? 1 : 0; float v1 = lv[i1];
#pragma unroll
  for (int rr = 0; rr < R; ++rr)
    if (rr != i0 && lv[rr] > v1) { v1 = lv[rr]; i1 = rr; }
  float se = 0.f;
#pragma unroll
  for (int rr = 0; rr < R; ++rr) se += expf(lv[rr] - v0);
  float p = expf(acc - v0) / se;
  if (r == 0) {
    float e10 = expf(v1 - v0);
    top2[b] = make_int2(i0, i1);
    gwv[b]  = make_float2(1.f / (1.f + e10), e10 / (1.f + e10));
  }
  float pa = p;
  int   ca = (r == i0 ? 1 : 0) + (r == i1 ? 1 : 0);
#pragma unroll
  for (int m = 8; m < 64; m <<= 1) {
    pa += __shfl_xor(pa, m);
    ca += __shfl_xor(ca, m);
  }
  if (l < 8) { atomicAdd(&psl[r], pa); atomicAdd(&cl[r], ca); }
  __syncthreads();
  if (tid < R) { atomicAdd(&ps[tid], psl[tid]); atomicAdd(&counts[tid], cl[tid]); }
}

// ---------------- scatter: per-router lists (pad-128 bases) + aux + offs ---
__global__ __launch_bounds__(256) void k_scatter(
    const int2* __restrict__ top2, const int* __restrict__ counts,
    const float* __restrict__ ps, int* __restrict__ cursors,
    int* __restrict__ list, int2* __restrict__ posmap,
    int* __restrict__ offs_g, float* __restrict__ out_aux)
{
  __shared__ int lc[R];
  __shared__ int lbase[R];
  __shared__ int offs[R];
  int tid = threadIdx.x;
  if (tid < R) lc[tid] = 0;
  __syncthreads();
  if (tid == 0) {
    int o = 0;
    for (int r2 = 0; r2 < R; ++r2) { offs[r2] = o; o += (min(counts[r2], B) + 127) & ~127; }
  }
  __syncthreads();
  int b = min(blockIdx.x * 256 + tid, B - 1);
  int2 t = top2[b];
  t.x &= 7; t.y &= 7;
  int p0 = atomicAdd(&lc[t.x], 1);
  int p1 = atomicAdd(&lc[t.y], 1);
  __syncthreads();
  if (tid < R) lbase[tid] = atomicAdd(&cursors[tid], lc[tid]);
  __syncthreads();
  int i0 = min(offs[t.x] + lbase[t.x] + p0, NPOS - 1);
  int i1 = min(offs[t.y] + lbase[t.y] + p1, NPOS - 1);
  list[i0] = b * 2 + 0;
  list[i1] = b * 2 + 1;
  posmap[b] = make_int2(i0, i1);
  if (blockIdx.x == 0 && tid == 0) {
    float s = 0.f;
    for (int r2 = 0; r2 < R; ++r2) {
      s += (ps[r2] / (float)B) * ((float)min(counts[r2], B) / (float)B);
      offs_g[r2] = offs[r2];
    }
    out_aux[0] = (float)R * s * 0.05f;
  }
}

// ---------------- projgemm: fused full-K GEMM + bias + l2norm + writeout ---
// Tile 64 rows x 64 h; 128 threads = 8 rowgroups x 16 colgroups; 8x4/lane
// (same FMA:LDS ratio as the 128-row version but grid 400 -> full CU
// coverage, LDS 64 KB -> 2 blocks/CU co-resident). 6 k-stages of 64,
// double-buffered with register prefetch; one barrier per stage.
// grid 400 = 128 evn tiles + <=272 xun tiles (pad-128 segs, 128-aligned
// so 64-row tiles never straddle a segment).
// FP accumulation order per output row is unchanged (k sequential 0..383,
// same fmaf grouping, same 16-lane norm tree) -> outputs bitwise identical.
__global__ __launch_bounds__(128) void k_projgemm(
    const float* __restrict__ re, const float* __restrict__ x,
    const float* __restrict__ Vw, const float* __restrict__ Uw,
    const float* __restrict__ Vb, const float* __restrict__ Ub,
    const int* __restrict__ list, const int* __restrict__ counts,
    const int* __restrict__ offs, float* __restrict__ evnC,
    float* __restrict__ xunP)
{
  __shared__ __align__(16) float At[2][64 * 64];   // [buf][k][row]  32 KB
  __shared__ __align__(16) float Wt[2][64 * 64];   // [buf][k][h]    32 KB
  int tid = threadIdx.x;
  int tile = blockIdx.x;
  int rowg0 = tile * 64;

  int srow = tid & 63, kh = tid >> 6;           // A staging: 2 threads/row
  const float* Wsrc;
  const float* arow;
  int r = 0;
  bool isE = (tile < 128);
  if (isE) {
    r = rowg0 >> 10;
    Wsrc = Vw + (size_t)r * (D * H);
    arow = re + (size_t)((rowg0 & 1023) + srow) * D;
  } else {
    int pos0 = rowg0 - 8192;
    int tot = offs[R - 1] + ((min(counts[R - 1], B) + 127) & ~127);
    if (pos0 >= tot) return;
    for (int rr = 0; rr < R; ++rr) if (pos0 >= offs[rr]) r = rr;
    Wsrc = Uw + (size_t)r * (D * H);
    int gl = list[min(pos0 + srow, NPOS - 1)];
    gl = min(max(gl, 0), 2 * B - 1);
    arow = x + (size_t)(gl >> 1) * D;
  }
  const float4* arow4 = (const float4*)arow;
  const float4* Wsrc4 = (const float4*)Wsrc;

  int rg = tid >> 4, cg = tid & 15;             // compute roles: 8 x 16
  float acc[8][4];
#pragma unroll
  for (int i = 0; i < 8; ++i)
#pragma unroll
    for (int j = 0; j < 4; ++j) acc[i][j] = 0.f;

  float4 va[8], vw[8];                          // in-flight stage registers

  // --- prologue: stage 0 ---
#pragma unroll
  for (int q = 0; q < 8; ++q)
    va[q] = arow4[kh * 8 + q];                  // k = kh*32 + q*4 .. +3
#pragma unroll
  for (int q = 0; q < 8; ++q) {
    int idx = tid + 128 * q;
    int k = idx >> 4, h4 = idx & 15;
    vw[q] = Wsrc4[(size_t)k * 16 + h4];
  }
#pragma unroll
  for (int q = 0; q < 8; ++q) {
    int k0 = kh * 32 + q * 4;
    At[0][(k0 + 0) * 64 + srow] = va[q].x;
    At[0][(k0 + 1) * 64 + srow] = va[q].y;
    At[0][(k0 + 2) * 64 + srow] = va[q].z;
    At[0][(k0 + 3) * 64 + srow] = va[q].w;
  }
#pragma unroll
  for (int q = 0; q < 8; ++q) {
    int idx = tid + 128 * q;
    int k = idx >> 4, h4 = idx & 15;
    *(float4*)&Wt[0][k * 64 + h4 * 4] = vw[q];
  }
  __syncthreads();

  for (int kt = 0; kt < 6; ++kt) {
    int cur = kt & 1;
    if (kt < 5) {                               // issue next stage's loads NOW
      int kb4 = (kt + 1) * 16;                  // f4 index of stage base
#pragma unroll
      for (int q = 0; q < 8; ++q)
        va[q] = arow4[kb4 + kh * 8 + q];
#pragma unroll
      for (int q = 0; q < 8; ++q) {
        int idx = tid + 128 * q;
        int k = idx >> 4, h4 = idx & 15;
        vw[q] = Wsrc4[(size_t)((kt + 1) * 64 + k) * 16 + h4];
      }
    }
    {
      const float4* At4 = (const float4*)&At[cur][0];
      const float4* Wt4 = (const float4*)&Wt[cur][0];
#pragma unroll 8
      for (int k = 0; k < 64; ++k) {            // compute current stage
        float4 a0 = At4[(k * 64 + rg * 8) >> 2];
        float4 a1 = At4[(k * 64 + rg * 8 + 4) >> 2];
        float4 w4 = Wt4[(k * 64 + cg * 4) >> 2];
        const float* a0p = (const float*)&a0;
        const float* a1p = (const float*)&a1;
        const float* wp  = (const float*)&w4;
#pragma unroll
        for (int i = 0; i < 4; ++i)
#pragma unroll
          for (int j = 0; j < 4; ++j) {
            acc[i][j]     = fmaf(a0p[i], wp[j], acc[i][j]);
            acc[i + 4][j] = fmaf(a1p[i], wp[j], acc[i + 4][j]);
          }
      }
    }
    if (kt < 5) {                               // write next stage to alt buf
      int nxt = cur ^ 1;
#pragma unroll
      for (int q = 0; q < 8; ++q) {
        int k0 = kh * 32 + q * 4;
        At[nxt][(k0 + 0) * 64 + srow] = va[q].x;
        At[nxt][(k0 + 1) * 64 + srow] = va[q].y;
        At[nxt][(k0 + 2) * 64 + srow] = va[q].z;
        At[nxt][(k0 + 3) * 64 + srow] = va[q].w;
      }
#pragma unroll
      for (int q = 0; q < 8; ++q) {
        int idx = tid + 128 * q;
        int k = idx >> 4, h4 = idx & 15;
        *(float4*)&Wt[nxt][k * 64 + h4 * 4] = vw[q];
      }
    }
    __syncthreads();
  }

  // ---- epilogue: bias + row L2-norm (row = rg*8+i; its 64 h on 16 cg lanes)
  const float* bsrc = (isE ? Vb : Ub) + r * H + cg * 4;
  float4 bv = *(const float4*)bsrc;
#pragma unroll
  for (int i = 0; i < 8; ++i) {
    acc[i][0] += bv.x;
    acc[i][1] += bv.y;
    acc[i][2] += bv.z;
    acc[i][3] += bv.w;
    float ss = acc[i][0] * acc[i][0] + acc[i][1] * acc[i][1]
             + acc[i][2] * acc[i][2] + acc[i][3] * acc[i][3];
#pragma unroll
    for (int m = 1; m < 16; m <<= 1) ss += __shfl_xor(ss, m);
    float dn = fmaxf(sqrtf(ss), 1e-12f);
    acc[i][0] /= dn; acc[i][1] /= dn; acc[i][2] /= dn; acc[i][3] /= dn;
  }

  if (!isE) {
    int pos0 = rowg0 - 8192;
#pragma unroll
    for (int i = 0; i < 8; ++i) {
      float4 o;
      o.x = acc[i][0]; o.y = acc[i][1]; o.z = acc[i][2]; o.w = acc[i][3];
      *(float4*)&xunP[(size_t)(pos0 + rg * 8 + i) * H + cg * 4] = o;
    }
    return;
  }

  // evn: tile's 64 e-rows == one chunk; transpose via pad-66 LDS scratch,
  // then write the contiguous 16 KB [h][e'] block fully coalesced.
  float* scratch = &At[0][0];                   // needs 64*66=4224 < 8192 fl
  int cidx = (rowg0 & 1023) >> 6;
  // final loop iteration ended with __syncthreads(): all FMA reads done
#pragma unroll
  for (int i = 0; i < 8; ++i)                   // scratch[h*66 + e_local]
#pragma unroll
    for (int j = 0; j < 4; ++j)
      scratch[(cg * 4 + j) * 66 + rg * 8 + i] = acc[i][j];
  __syncthreads();
  float* dst = evnC + (size_t)(r * NCHUNK + cidx) * 64 * 64;
#pragma unroll
  for (int q = 0; q < 8; ++q) {
    int idx = tid + 128 * q;                    // 0..1023
    int h = idx >> 4, f4 = idx & 15;
    float4 o;
    o.x = scratch[h * 66 + f4 * 4 + 0];
    o.y = scratch[h * 66 + f4 * 4 + 1];
    o.z = scratch[h * 66 + f4 * 4 + 2];
    o.w = scratch[h * 66 + f4 * 4 + 3];
    *(float4*)&dst[h * 64 + f4 * 4] = o;
  }
}

// ---------------- pass1: scores GEMM -> __expf -> chunk sums ---------------
// tile 128 pos x 128 e; 8x8/thread; 32-k x2 stages, LDS 32 KB.
// T14 register-prefetch: stage-1 global loads issue before the first
// barrier and drain during stage-0 compute. 3 barriers (was 4), one
// exposed L2 chain (was 2). Same addresses, same k order -> bitwise same.
__global__ __launch_bounds__(256) void k_pass1(
    const float* __restrict__ evnC, const float* __restrict__ xunP,
    const int* __restrict__ counts, const int* __restrict__ offs,
    float* __restrict__ C)
{
  __shared__ __align__(16) float Xt[32 * 128];
  __shared__ __align__(16) float Et[32 * 128];
  int tid = threadIdx.x;
  int bid = blockIdx.x;
  int et    = bid & 7;
  int stile = (bid >> 3) & 63;
  int r     = bid >> 9;
  int cnt = min(counts[r], B);
  if (cnt <= 0 || stile * 128 >= cnt) return;
  int off = offs[r] + stile * 128;
  int n = min(128, cnt - stile * 128);

  int sg = tid >> 4, egr = tid & 15;
  float acc[8][8];
#pragma unroll
  for (int i = 0; i < 8; ++i)
#pragma unroll
    for (int j = 0; j < 8; ++j) acc[i][j] = 0.f;

  int srow = tid >> 1, shalf = tid & 1;
  int src = min(srow, n - 1);
  const float4* xsrc = (const float4*)(xunP + (size_t)(off + src) * H);

  float4 xv[4], ev[4];
  // ---- stage 0 loads
#pragma unroll
  for (int q = 0; q < 4; ++q) xv[q] = xsrc[shalf * 4 + q];
#pragma unroll
  for (int q = 0; q < 4; ++q) {
    int idx = tid + 256 * q;
    int h = idx >> 5, e4 = idx & 31;
    int cc = et * 2 + (e4 >> 4);
    ev[q] = *(const float4*)(evnC + ((size_t)(r * NCHUNK + cc) * 64 + h) * 64
                             + (e4 & 15) * 4);
  }
  // ---- stage 0 LDS writes (fresh LDS: no barrier needed before)
#pragma unroll
  for (int q = 0; q < 4; ++q) {
    int hb = shalf * 16 + q * 4;
    Xt[(hb + 0) * 128 + srow] = xv[q].x;
    Xt[(hb + 1) * 128 + srow] = xv[q].y;
    Xt[(hb + 2) * 128 + srow] = xv[q].z;
    Xt[(hb + 3) * 128 + srow] = xv[q].w;
  }
#pragma unroll
  for (int q = 0; q < 4; ++q) {
    int idx = tid + 256 * q;
    int h = idx >> 5, e4 = idx & 31;
    *(float4*)&Et[h * 128 + e4 * 4] = ev[q];
  }
  // ---- stage 1 loads: issue now, drain under stage-0 compute
#pragma unroll
  for (int q = 0; q < 4; ++q) xv[q] = xsrc[8 + shalf * 4 + q];
#pragma unroll
  for (int q = 0; q < 4; ++q) {
    int idx = tid + 256 * q;
    int h = idx >> 5, e4 = idx & 31;
    int cc = et * 2 + (e4 >> 4);
    ev[q] = *(const float4*)(evnC + ((size_t)(r * NCHUNK + cc) * 64 + 32 + h) * 64
                             + (e4 & 15) * 4);
  }
  __syncthreads();

  auto compute32 = [&]() {
#pragma unroll 4
    for (int k = 0; k < 32; ++k) {
      float4 xa = *(const float4*)&Xt[k * 128 + sg * 4];
      float4 xb = *(const float4*)&Xt[k * 128 + 64 + sg * 4];
      float4 ea = *(const float4*)&Et[k * 128 + egr * 4];
      float4 eb = *(const float4*)&Et[k * 128 + 64 + egr * 4];
      const float* pa = (const float*)&xa;
      const float* pb = (const float*)&xb;
      const float* qa = (const float*)&ea;
      const float* qb = (const float*)&eb;
#pragma unroll
      for (int i = 0; i < 4; ++i)
#pragma unroll
        for (int j = 0; j < 4; ++j) {
          acc[i][j]         = fmaf(pa[i], qa[j], acc[i][j]);
          acc[i][j + 4]     = fmaf(pa[i], qb[j], acc[i][j + 4]);
          acc[i + 4][j]     = fmaf(pb[i], qa[j], acc[i + 4][j]);
          acc[i + 4][j + 4] = fmaf(pb[i], qb[j], acc[i + 4][j + 4]);
        }
    }
  };

  compute32();                                  // kst = 0
  __syncthreads();
  // ---- stage 1 LDS writes
#pragma unroll
  for (int q = 0; q < 4; ++q) {
    int hb = shalf * 16 + q * 4;
    Xt[(hb + 0) * 128 + srow] = xv[q].x;
    Xt[(hb + 1) * 128 + srow] = xv[q].y;
    Xt[(hb + 2) * 128 + srow] = xv[q].z;
    Xt[(hb + 3) * 128 + srow] = xv[q].w;
  }
#pragma unroll
  for (int q = 0; q < 4; ++q) {
    int idx = tid + 256 * q;
    int h = idx >> 5, e4 = idx & 31;
    *(float4*)&Et[h * 128 + e4 * 4] = ev[q];
  }
  __syncthreads();
  compute32();                                  // kst = 1

#pragma unroll
  for (int i = 0; i < 8; ++i) {
    float cA = __expf(acc[i][0]) + __expf(acc[i][1]) + __expf(acc[i][2]) + __expf(acc[i][3]);
    float cB = __expf(acc[i][4]) + __expf(acc[i][5]) + __expf(acc[i][6]) + __expf(acc[i][7]);
#pragma unroll
    for (int m = 1; m < 16; m <<= 1) {
      cA += __shfl_xor(cA, m);
      cB += __shfl_xor(cB, m);
    }
    int s = (i < 4) ? (sg * 4 + i) : (64 + sg * 4 + i - 4);
    if (egr == 0 && s < n) {
      C[(size_t)(off + s) * NCHUNK + et * 2]     = cA;
      C[(size_t)(off + s) * NCHUNK + et * 2 + 1] = cB;
    }
  }
}

// ---------------- pass2: chunk-level inverse-CDF, recompute 1 chunk --------
// Chunk block is 16 KB contiguous: wave reads it as 16 coalesced 1KB f4 loads
// (each 64B line requested exactly once). Lane l covers e' = (l&15)*4..+3,
// h-residue l>>4; h-reduce via 2 shfl_xor; 16-lane scan for the CDF.
__global__ __launch_bounds__(256) void k_pass2(
    const float* __restrict__ evnC, const float* __restrict__ xunP,
    const float* __restrict__ C, const int2* __restrict__ top2,
    const int2* __restrict__ posmap, const float2* __restrict__ gwv,
    const float* __restrict__ rnd, float* __restrict__ out)
{
  __shared__ __align__(16) float sxu[4][2][64];
  int tid = threadIdx.x;
  int lane = tid & 63;
  int w = tid >> 6;
  int b = blockIdx.x * 4 + w;                   // grid 2048*4 == B exactly
  int2 t2 = top2[b];
  t2.x &= 7; t2.y &= 7;
  int2 pm = posmap[b];
  pm.x = min(max(pm.x, 0), NPOS - 1);
  pm.y = min(max(pm.y, 0), NPOS - 1);
  float2 gw = gwv[b];
  float rv = rnd[b];

  sxu[w][0][lane] = xunP[(size_t)pm.x * H + lane];
  sxu[w][1][lane] = xunP[(size_t)pm.y * H + lane];

  const float4* C04 = (const float4*)(C + (size_t)pm.x * NCHUNK);
  const float4* C14 = (const float4*)(C + (size_t)pm.y * NCHUNK);
  float c0[NCHUNK], c1[NCHUNK];
#pragma unroll
  for (int q = 0; q < 4; ++q) {
    float4 v0 = C04[q], v1 = C14[q];
    c0[q*4+0]=v0.x; c0[q*4+1]=v0.y; c0[q*4+2]=v0.z; c0[q*4+3]=v0.w;
    c1[q*4+0]=v1.x; c1[q*4+1]=v1.y; c1[q*4+2]=v1.z; c1[q*4+3]=v1.w;
  }
  float S0 = 0.f, S1 = 0.f;
#pragma unroll
  for (int j = 0; j < NCHUNK; ++j) { S0 += c0[j]; S1 += c1[j]; }
  float a0 = gw.x / S0, a1 = gw.y / S1;
  int cstar = -1; float prefix = 0.f; float run = 0.f;
#pragma unroll
  for (int j = 0; j < NCHUNK; ++j) {
    float nrun = run + (c0[j] * a0 + c1[j] * a1);
    if (cstar < 0 && nrun > rv) { cstar = j; prefix = run; }
    run = nrun;
  }
  float rtgt = rv;
  if (cstar < 0) { cstar = 0; prefix = 0.f; rtgt = -1.0f; }

  __syncthreads();                              // sxu visible (no divergence)

  const float4* E0 = (const float4*)(evnC + (size_t)(t2.x * NCHUNK + cstar) * 64 * 64);
  const float4* E1 = (const float4*)(evnC + (size_t)(t2.y * NCHUNK + cstar) * 64 * 64);
  const float* x0 = &sxu[w][0][0];
  const float* x1 = &sxu[w][1][0];
  int hq = lane >> 4;
  float d0[4] = {0.f, 0.f, 0.f, 0.f};
  float d1[4] = {0.f, 0.f, 0.f, 0.f};
#pragma unroll
  for (int q = 0; q < 16; ++q) {                // f4 at linear q*256 + lane*4:
    float4 e0 = E0[q * 64 + lane];              //   h = q*4 + hq, e' = (lane&15)*4
    float4 e1 = E1[q * 64 + lane];
    float w0 = x0[q * 4 + hq];
    float w1 = x1[q * 4 + hq];
    d0[0] = fmaf(e0.x, w0, d0[0]); d0[1] = fmaf(e0.y, w0, d0[1]);
    d0[2] = fmaf(e0.z, w0, d0[2]); d0[3] = fmaf(e0.w, w0, d0[3]);
    d1[0] = fmaf(e1.x, w1, d1[0]); d1[1] = fmaf(e1.y, w1, d1[1]);
    d1[2] = fmaf(e1.z, w1, d1[2]); d1[3] = fmaf(e1.w, w1, d1[3]);
  }
#pragma unroll
  for (int j = 0; j < 4; ++j) {                 // combine h-residues
    d0[j] += __shfl_xor(d0[j], 16);
    d0[j] += __shfl_xor(d0[j], 32);
    d1[j] += __shfl_xor(d1[j], 16);
    d1[j] += __shfl_xor(d1[j], 32);
  }
  float rea[4], inc[4];
  float trun = 0.f;
#pragma unroll
  for (int j = 0; j < 4; ++j) {
    rea[j] = __expf(d0[j]) * a0 + __expf(d1[j]) * a1;
    trun += rea[j];
    inc[j] = trun;
  }
  float sc = trun;                              // width-16 inclusive scan
#pragma unroll
  for (int d = 1; d < 16; d <<= 1) {
    float o = __shfl_up(sc, d, 16);
    if ((lane & 15) >= d) sc += o;
  }
  float base = prefix + (sc - trun);            // exclusive prefix for this lane
  unsigned long long m2 = __ballot(base + inc[3] > rtgt) & 0xFFFFull;
  int lstar = (m2 == 0ull) ? 15 : (int)__builtin_ctzll(m2);
  int jloc = 3;
  if (base + inc[2] > rtgt) jloc = 2;
  if (base + inc[1] > rtgt) jloc = 1;
  if (base + inc[0] > rtgt) jloc = 0;
  float pl = (jloc == 0) ? rea[0] : (jloc == 1) ? rea[1] : (jloc == 2) ? rea[2] : rea[3];
  int   js = __shfl(jloc, lstar);
  float p  = __shfl(pl, lstar);
  if (lane == 0) {
    int sel = cstar * CHUNK_E + lstar * 4 + js;
    out[b]     = (float)sel;
    out[B + b] = logf(p);
  }
}

// ---------------------------------------------------------------------------
extern "C" void kernel_launch(void* const* d_in, const int* in_sizes, int n_in,
                              void* d_out, int out_size, void* d_ws, size_t ws_size,
                              hipStream_t stream)
{
  (void)in_sizes; (void)n_in; (void)out_size; (void)ws_size;
  const float* x      = (const float*)d_in[0];
  const float* re     = (const float*)d_in[1];
  const float* rnd    = (const float*)d_in[2];
  const float* gate_w = (const float*)d_in[3];
  const float* gate_b = (const float*)d_in[4];
  const float* Uw     = (const float*)d_in[5];
  const float* Ub     = (const float*)d_in[6];
  const float* Vw     = (const float*)d_in[7];
  const float* Vb     = (const float*)d_in[8];
  char* ws = (char*)d_ws;
  int*    counts  = (int*)(ws + WS_CNT);
  int*    cursors = (int*)(ws + WS_CUR);
  float*  ps      = (float*)(ws + WS_PS);
  int*    offs    = (int*)(ws + WS_OFFS);
  int2*   top2    = (int2*)(ws + WS_TOP2);
  float2* gwv     = (float2*)(ws + WS_GW);
  int2*   posmap  = (int2*)(ws + WS_POSM);
  int*    list    = (int*)(ws + WS_LIST);
  float*  evnC    = (float*)(ws + WS_EVN);
  float*  xunP    = (float*)(ws + WS_XUN);
  float*  Cc      = (float*)(ws + WS_C);
  float* out = (float*)d_out;

  hipMemsetAsync(ws, 0, 128, stream);
  k_gate    <<<256,  256, 0, stream>>>(x, gate_w, gate_b, top2, gwv, counts, ps);
  k_scatter <<<32,   256, 0, stream>>>(top2, counts, ps, cursors, list, posmap, offs, out + 2 * B);
  k_projgemm<<<400,  128, 0, stream>>>(re, x, Vw, Uw, Vb, Ub, list, counts, offs, evnC, xunP);
  k_pass1   <<<4096, 256, 0, stream>>>(evnC, xunP, counts, offs, Cc);
  k_pass2   <<<2048, 256, 0, stream>>>(evnC, xunP, Cc, top2, posmap, gwv, rnd, out);
}